// Round 1
// 1256.052 us; speedup vs baseline: 1.3986x; 1.3986x over previous
//
#include <hip/hip_runtime.h>

typedef unsigned short u16;
typedef __attribute__((ext_vector_type(8))) short bf16x8;
typedef __attribute__((ext_vector_type(4))) float f32x4;

__device__ __forceinline__ float fs(float f) {
    return (f == f && fabsf(f) < 1e30f) ? f : 0.f;
}
__device__ __forceinline__ float fin(float v) {
    return (v == v && fabsf(v) < 1e30f) ? v : 555.0f;
}
__device__ __forceinline__ u16 f2b(float f) {
    union { float f; unsigned int i; } w; w.f = f;
    unsigned int r = w.i + 0x7FFFu + ((w.i >> 16) & 1u);
    return (u16)(r >> 16);
}
__device__ __forceinline__ float gelu_f(float x) {
    return 0.5f * x * (1.0f + erff(x * 0.70710678118654752440f));
}

__global__ void fill_kernel(float* __restrict__ out, int n, float val) {
    int i = blockIdx.x * 256 + threadIdx.x;
    if (i < n) out[i] = val;
}

// nbr row (30) + sdiff row (12), one thread per (b,k)
__global__ void k_prep(const float* __restrict__ qobs, const float* __restrict__ qmask,
                       const float* __restrict__ rshift, const int* __restrict__ rsmask,
                       const int* __restrict__ qcode, const int* __restrict__ rcodes,
                       const float* __restrict__ rdist, const float* __restrict__ rc_table,
                       const float* __restrict__ E_res,
                       float* __restrict__ nbr, float* __restrict__ sdiff, int NBc)
{
    int gk = blockIdx.x * 256 + threadIdx.x;
    if (gk >= NBc) return;
    int b = gk >> 5;
    int qc = qcode[b], rc = rcodes[gk];
    int qi = min(max(qc, 0), 20), ri = min(max(rc, 0), 20);
    float dist = fs(rdist[gk]);
    float same = (rc == qc) ? 1.f : 0.f;
    float* nr = nbr + (size_t)gk * 30;
    float* sd = sdiff + (size_t)gk * 12;
    for (int s = 0; s < 6; s++) {
        float rs = fs(rshift[gk * 6 + s]);
        bool m = rsmask[gk * 6 + s] != 0;
        float rq = rc_table[qi * 6 + s];
        float rr = rc_table[ri * 6 + s];
        bool rcv = (rq == rq) && (rr == rr) && fabsf(rq) < 1e30f && fabsf(rr) < 1e30f;
        float sh = (m && rcv) ? (rq + rs - rr) : rs;
        nr[s] = sh;
        nr[6 + s] = m ? 1.f : 0.f;
        float qm = fs(qmask[b * 6 + s]);
        sd[s] = (fs(qobs[b * 6 + s]) - sh) * qm;
        sd[6 + s] = qm;
    }
    for (int j = 0; j < 16; j++) nr[12 + j] = fs(E_res[ri * 16 + j]);
    nr[28] = dist;
    nr[29] = same;
}

__global__ void k_stats(const float* __restrict__ nbr, const int* __restrict__ rvalid,
                        float* __restrict__ pst, float* __restrict__ gst,
                        float* __restrict__ anyv, int BCc)
{
    int b = blockIdx.x * 256 + threadIdx.x;
    if (b >= BCc) return;
    float svf = 0.f, sdm = 0.f, mdm = -1e30f, ssm = 0.f;
    for (int k = 0; k < 32; k++) {
        const float* nr = nbr + (size_t)(b * 32 + k) * 30;
        float vf = (rvalid[b * 32 + k] != 0) ? 1.f : 0.f;
        float dm = vf * nr[28];
        svf += vf; sdm += dm; mdm = fmaxf(mdm, dm); ssm += vf * nr[29];
    }
    for (int s = 0; s < 6; s++) {
        float cnt = 0.f, msum = 0.f, mdist = 0.f, mst = 0.f;
        for (int k = 0; k < 32; k++) {
            const float* nr = nbr + (size_t)(b * 32 + k) * 30;
            float vf = (rvalid[b * 32 + k] != 0) ? 1.f : 0.f;
            float vm = vf * nr[6 + s];
            cnt += vm; msum += nr[s] * vm; mdist += nr[28] * vm; mst += nr[29] * vm;
        }
        float inv = 1.f / (cnt + 1e-8f);
        float mean = msum * inv;
        float var = 0.f;
        for (int k = 0; k < 32; k++) {
            const float* nr = nbr + (size_t)(b * 32 + k) * 30;
            float vf = (rvalid[b * 32 + k] != 0) ? 1.f : 0.f;
            float vm = vf * nr[6 + s];
            float dv = nr[s] - mean;
            var += dv * dv * vm;
        }
        var *= inv;
        float* p = pst + (size_t)b * 24 + s * 4;
        p[0] = cnt * (1.f / 32.f);
        p[1] = fminf(fmaxf(log1pf(var), 0.f), 5.f) * 0.2f;
        p[2] = mdist * inv;
        p[3] = mst * inv;
    }
    float* g = gst + (size_t)b * 4;
    g[0] = sdm / (svf + 1e-8f);
    g[1] = mdm;
    g[2] = svf * (1.f / 32.f);
    g[3] = ssm * (1.f / 32.f);
    anyv[b] = (svf > 0.f) ? 1.f : 0.f;
}

// scalar GEMM (kept for small-N cases): C = act(A@B + bias)
template <int ACT>
__global__ void k_gemm(const float* __restrict__ A, int lda,
                       const float* __restrict__ B, const float* __restrict__ bias,
                       float* __restrict__ C, int M, int N, int K)
{
    int id = blockIdx.x * 256 + threadIdx.x;
    if (id >= M * N) return;
    int m = id / N, n = id - m * N;
    float acc = bias ? fs(bias[n]) : 0.f;
    const float* Ap = A + (size_t)m * lda;
    for (int k = 0; k < K; k++) acc += Ap[k] * fs(B[(size_t)k * N + n]);
    C[id] = (ACT == 1) ? gelu_f(acc) : acc;
}

// bf16 MFMA GEMM: C(M,N) = act(A(M,K)@B(K,N) + bias), fp32 in/out, bf16 compute.
// M % 64 == 0 and N % 64 == 0 required (all call sites satisfy this).
template <int ACT>
__global__ __launch_bounds__(256) void k_gemm_mfma(
    const float* __restrict__ A, int lda,
    const float* __restrict__ B, int ldb,
    const float* __restrict__ bias,
    float* __restrict__ C, int ldc, int K)
{
    __shared__ u16 As[64 * 40];
    __shared__ u16 Bs[64 * 40];
    const int t = threadIdx.x;
    const int lane = t & 63, wave = t >> 6;
    const int m0 = blockIdx.y << 6, n0 = blockIdx.x << 6;
    const int wm = (wave & 1) << 5, wn = (wave >> 1) << 5;
    const int sr = t >> 2, sk = (t & 3) << 3;
    const int bn = t & 63, bw = t >> 6;
    const int frm = lane & 15, frq = lane >> 4, frk = frq << 3;
    const f32x4 z = {0.f, 0.f, 0.f, 0.f};
    f32x4 acc[2][2] = {{z, z}, {z, z}};
    for (int k0 = 0; k0 < K; k0 += 32) {
        {
            const float* p = A + (size_t)(m0 + sr) * lda + k0 + sk;
#pragma unroll
            for (int i = 0; i < 8; i++)
                As[sr * 40 + sk + i] = (k0 + sk + i < K) ? f2b(fs(p[i])) : (u16)0;
        }
#pragma unroll
        for (int kk = bw; kk < 32; kk += 4)
            Bs[bn * 40 + kk] = (k0 + kk < K) ? f2b(fs(B[(size_t)(k0 + kk) * ldb + n0 + bn])) : (u16)0;
        __syncthreads();
        bf16x8 a0 = *(const bf16x8*)&As[(wm + frm) * 40 + frk];
        bf16x8 a1 = *(const bf16x8*)&As[(wm + 16 + frm) * 40 + frk];
        bf16x8 b0 = *(const bf16x8*)&Bs[(wn + frm) * 40 + frk];
        bf16x8 b1 = *(const bf16x8*)&Bs[(wn + 16 + frm) * 40 + frk];
        acc[0][0] = __builtin_amdgcn_mfma_f32_16x16x32_bf16(a0, b0, acc[0][0], 0, 0, 0);
        acc[0][1] = __builtin_amdgcn_mfma_f32_16x16x32_bf16(a0, b1, acc[0][1], 0, 0, 0);
        acc[1][0] = __builtin_amdgcn_mfma_f32_16x16x32_bf16(a1, b0, acc[1][0], 0, 0, 0);
        acc[1][1] = __builtin_amdgcn_mfma_f32_16x16x32_bf16(a1, b1, acc[1][1], 0, 0, 0);
        __syncthreads();
    }
#pragma unroll
    for (int mi = 0; mi < 2; mi++) {
#pragma unroll
        for (int ni = 0; ni < 2; ni++) {
            int col = n0 + wn + (ni << 4) + frm;
            float bv = bias ? fs(bias[col]) : 0.f;
#pragma unroll
            for (int r = 0; r < 4; r++) {
                int row = m0 + wm + (mi << 4) + (frq << 2) + r;
                float v = acc[mi][ni][r] + bv;
                if (ACT == 1) v = gelu_f(v);
                C[(size_t)row * ldc + col] = v;
            }
        }
    }
}

// per-head Q projection via MFMA with transposed B:
// Qp[b, hd*384+j] = sum_d Qh[b, hd*64+d] * Wak[j, hd*64+d]
// grid (6 nblk, BCc/64 mblk, 6 heads)
__global__ __launch_bounds__(256) void k_qp_mfma(
    const float* __restrict__ Qh, const float* __restrict__ Wak,
    float* __restrict__ Qp)
{
    __shared__ u16 As[64 * 40];
    __shared__ u16 Bs[64 * 40];
    const int t = threadIdx.x;
    const int lane = t & 63, wave = t >> 6;
    const int m0 = blockIdx.y << 6, n0 = blockIdx.x << 6, hd = blockIdx.z;
    const int wm = (wave & 1) << 5, wn = (wave >> 1) << 5;
    const int sr = t >> 2, sk = (t & 3) << 3;
    const int frm = lane & 15, frq = lane >> 4, frk = frq << 3;
    const f32x4 z = {0.f, 0.f, 0.f, 0.f};
    f32x4 acc[2][2] = {{z, z}, {z, z}};
    for (int k0 = 0; k0 < 64; k0 += 32) {
        {
            const float* p = Qh + (size_t)(m0 + sr) * 384 + hd * 64 + k0 + sk;
#pragma unroll
            for (int i = 0; i < 8; i++) As[sr * 40 + sk + i] = f2b(fs(p[i]));
        }
        {   // B transposed: Bs[n][k] = Wak[(n0+n), hd*64 + k0+k]
            const float* p = Wak + (size_t)(n0 + sr) * 384 + hd * 64 + k0 + sk;
#pragma unroll
            for (int i = 0; i < 8; i++) Bs[sr * 40 + sk + i] = f2b(fs(p[i]));
        }
        __syncthreads();
        bf16x8 a0 = *(const bf16x8*)&As[(wm + frm) * 40 + frk];
        bf16x8 a1 = *(const bf16x8*)&As[(wm + 16 + frm) * 40 + frk];
        bf16x8 b0 = *(const bf16x8*)&Bs[(wn + frm) * 40 + frk];
        bf16x8 b1 = *(const bf16x8*)&Bs[(wn + 16 + frm) * 40 + frk];
        acc[0][0] = __builtin_amdgcn_mfma_f32_16x16x32_bf16(a0, b0, acc[0][0], 0, 0, 0);
        acc[0][1] = __builtin_amdgcn_mfma_f32_16x16x32_bf16(a0, b1, acc[0][1], 0, 0, 0);
        acc[1][0] = __builtin_amdgcn_mfma_f32_16x16x32_bf16(a1, b0, acc[1][0], 0, 0, 0);
        acc[1][1] = __builtin_amdgcn_mfma_f32_16x16x32_bf16(a1, b1, acc[1][1], 0, 0, 0);
        __syncthreads();
    }
#pragma unroll
    for (int mi = 0; mi < 2; mi++) {
#pragma unroll
        for (int ni = 0; ni < 2; ni++) {
            int col = n0 + wn + (ni << 4) + frm;
#pragma unroll
            for (int r = 0; r < 4; r++) {
                int row = m0 + wm + (mi << 4) + (frq << 2) + r;
                Qp[(size_t)row * 2304 + hd * 384 + col] = acc[mi][ni][r];
            }
        }
    }
}

// per-head attn-out projection via MFMA:
// attn[b, hd*64+n] = sum_j vms[b, hd*384+j] * Wav[j, hd*64+n] + bav[hd*64+n]
// grid (6 heads, BCc/64 mblk)
__global__ __launch_bounds__(256) void k_attnout_mfma(
    const float* __restrict__ vms, const float* __restrict__ Wav,
    const float* __restrict__ bav, float* __restrict__ attn)
{
    __shared__ u16 As[64 * 40];
    __shared__ u16 Bs[64 * 40];
    const int t = threadIdx.x;
    const int lane = t & 63, wave = t >> 6;
    const int m0 = blockIdx.y << 6, hd = blockIdx.x;
    const int wm = (wave & 1) << 5, wn = (wave >> 1) << 5;
    const int sr = t >> 2, sk = (t & 3) << 3;
    const int bn = t & 63, bw = t >> 6;
    const int frm = lane & 15, frq = lane >> 4, frk = frq << 3;
    const f32x4 z = {0.f, 0.f, 0.f, 0.f};
    f32x4 acc[2][2] = {{z, z}, {z, z}};
    for (int k0 = 0; k0 < 384; k0 += 32) {
        {
            const float* p = vms + (size_t)(m0 + sr) * 2304 + hd * 384 + k0 + sk;
#pragma unroll
            for (int i = 0; i < 8; i++) As[sr * 40 + sk + i] = f2b(fs(p[i]));
        }
#pragma unroll
        for (int kk = bw; kk < 32; kk += 4)
            Bs[bn * 40 + kk] = f2b(fs(Wav[(size_t)(k0 + kk) * 384 + hd * 64 + bn]));
        __syncthreads();
        bf16x8 a0 = *(const bf16x8*)&As[(wm + frm) * 40 + frk];
        bf16x8 a1 = *(const bf16x8*)&As[(wm + 16 + frm) * 40 + frk];
        bf16x8 b0 = *(const bf16x8*)&Bs[(wn + frm) * 40 + frk];
        bf16x8 b1 = *(const bf16x8*)&Bs[(wn + 16 + frm) * 40 + frk];
        acc[0][0] = __builtin_amdgcn_mfma_f32_16x16x32_bf16(a0, b0, acc[0][0], 0, 0, 0);
        acc[0][1] = __builtin_amdgcn_mfma_f32_16x16x32_bf16(a0, b1, acc[0][1], 0, 0, 0);
        acc[1][0] = __builtin_amdgcn_mfma_f32_16x16x32_bf16(a1, b0, acc[1][0], 0, 0, 0);
        acc[1][1] = __builtin_amdgcn_mfma_f32_16x16x32_bf16(a1, b1, acc[1][1], 0, 0, 0);
        __syncthreads();
    }
#pragma unroll
    for (int mi = 0; mi < 2; mi++) {
#pragma unroll
        for (int ni = 0; ni < 2; ni++) {
            int col = wn + (ni << 4) + frm;   // 0..63 within head
            float bv = fs(bav[hd * 64 + col]);
#pragma unroll
            for (int r = 0; r < 4; r++) {
                int row = m0 + wm + (mi << 4) + (frq << 2) + r;
                attn[(size_t)row * 384 + hd * 64 + col] = acc[mi][ni][r] + bv;
            }
        }
    }
}

// fused score-bias MLP: one block per b (192 threads); hid kept in LDS
__global__ __launch_bounds__(192) void k_mlpbias(
    const float* __restrict__ sdiff, const float* __restrict__ Wss1,
    const float* __restrict__ bss1, const float* __restrict__ Wss2,
    const float* __restrict__ bss2, float* __restrict__ bias_s)
{
    __shared__ float sdS[32 * 12];
    __shared__ float hidS[32 * 193];   // stride 193: bank = (k+n)%32, conflict-free
    const int b = blockIdx.x;
    const int t = threadIdx.x;
    for (int i = t; i < 384; i += 192) sdS[i] = sdiff[(size_t)b * 384 + i];
    __syncthreads();
    {
        float w[12];
#pragma unroll
        for (int j = 0; j < 12; j++) w[j] = fs(Wss1[j * 192 + t]);
        float b1 = fs(bss1[t]);
        for (int k = 0; k < 32; k++) {
            float acc = b1;
#pragma unroll
            for (int j = 0; j < 12; j++) acc += sdS[k * 12 + j] * w[j];
            hidS[k * 193 + t] = gelu_f(acc);
        }
    }
    __syncthreads();
    {
        int k = t / 6, s = t - k * 6;
        float acc = fs(bss2[s]);
        for (int n = 0; n < 192; n++) acc += hidS[k * 193 + n] * fs(Wss2[n * 6 + s]);
        bias_s[(size_t)(b * 32 + k) * 6 + s] = acc;
    }
}

__global__ void k_qkb(const float* __restrict__ Qh, const float* __restrict__ bak,
                      float* __restrict__ qkb, int BCc)
{
    int id = blockIdx.x * 256 + threadIdx.x;
    if (id >= BCc * 6) return;
    int b = id / 6, h = id - b * 6;
    float acc = 0.f;
    for (int d = 0; d < 64; d++)
        acc += Qh[(size_t)b * 384 + h * 64 + d] * fs(bak[h * 64 + d]);
    qkb[id] = acc;
}

// attention core: kv + scores + softmax + weighted-sum. Writes vms (b x 2304)
// into the Qp buffer (safe: Qp is copied to LDS before any write, per-block slice).
// kvs stride 385 (385%32==1) -> all stages bank-conflict-free.
__global__ __launch_bounds__(384) void k_attnblk(
    const float* __restrict__ nbr, const float* __restrict__ Wnp,
    const float* __restrict__ bnp, float* Qp /* in: Qp, out: vms */,
    const float* __restrict__ qkb, const float* __restrict__ bias_s,
    const int* __restrict__ rvalid, const float* __restrict__ anyv)
{
    __shared__ float kvs[32 * 385];   // 49280 B
    __shared__ float qS[2304];        // 9216 B
    __shared__ float nbs[960];        // 3840 B
    __shared__ float wsx[192];        // 768 B  -> total 63104 B
    const int b = blockIdx.x;
    const int t = threadIdx.x;
    for (int i = t; i < 960; i += 384) nbs[i] = nbr[(size_t)b * 960 + i];
    for (int i = t; i < 2304; i += 384) qS[i] = Qp[(size_t)b * 2304 + i];
    __syncthreads();
    {   // stage A: kv[k][t] = gelu(sum_j nbs[k][j]*Wnp[j][t] + bnp[t])
        float w[30];
#pragma unroll
        for (int j = 0; j < 30; j++) w[j] = fs(Wnp[j * 384 + t]);
        float bb = fs(bnp[t]);
        for (int k = 0; k < 32; k++) {
            float acc = bb;
#pragma unroll
            for (int j = 0; j < 30; j++) acc += nbs[k * 30 + j] * w[j];
            kvs[k * 385 + t] = gelu_f(acc);
        }
    }
    __syncthreads();
    {   // stage B: scores + wave-parallel softmax. wave w handles head w;
        // lanes 2p,2p+1 split the 384-dot into halves.
        const int p = t >> 1, half = t & 1;
        const int h = p >> 5, k = p & 31;
        const float* kr = &kvs[k * 385 + half * 192];
        const float* qr = &qS[h * 384 + half * 192];
        float acc = 0.f;
#pragma unroll 8
        for (int j = 0; j < 192; j++) acc += kr[j] * qr[j];
        acc += __shfl_xor(acc, 1);    // both halves now hold full dot
        float s = (acc + qkb[b * 6 + h]) * 0.125f + bias_s[(size_t)(b * 32 + k) * 6 + h];
        bool ve = (rvalid[b * 32 + k] != 0) || (anyv[b] == 0.f && k == 0);
        s = ve ? s : -10000.f;
        // reduce over k (32 distinct lanes per parity class): xor masks 2..32
        float mx = s;
        mx = fmaxf(mx, __shfl_xor(mx, 2));
        mx = fmaxf(mx, __shfl_xor(mx, 4));
        mx = fmaxf(mx, __shfl_xor(mx, 8));
        mx = fmaxf(mx, __shfl_xor(mx, 16));
        mx = fmaxf(mx, __shfl_xor(mx, 32));
        float e = expf(s - mx);
        float sum = e;
        sum += __shfl_xor(sum, 2);
        sum += __shfl_xor(sum, 4);
        sum += __shfl_xor(sum, 8);
        sum += __shfl_xor(sum, 16);
        sum += __shfl_xor(sum, 32);
        if (half == 0) wsx[h * 32 + k] = e / sum;
    }
    __syncthreads();
    {   // stage C: vms[h][t] = sum_k w[h][k]*kv[k][t]  -> global (reuse Qp buffer)
        float a0 = 0.f, a1 = 0.f, a2 = 0.f, a3 = 0.f, a4 = 0.f, a5 = 0.f;
        for (int k = 0; k < 32; k++) {
            float kvv = kvs[k * 385 + t];
            a0 += wsx[k] * kvv;
            a1 += wsx[32 + k] * kvv;
            a2 += wsx[64 + k] * kvv;
            a3 += wsx[96 + k] * kvv;
            a4 += wsx[128 + k] * kvv;
            a5 += wsx[160 + k] * kvv;
        }
        float* vp = Qp + (size_t)b * 2304;
        vp[t] = a0;
        vp[384 + t] = a1;
        vp[768 + t] = a2;
        vp[1152 + t] = a3;
        vp[1536 + t] = a4;
        vp[1920 + t] = a5;
    }
}

__global__ void k_ctxout(const float* __restrict__ ctx, const float* __restrict__ anyv,
                         const float* __restrict__ fctx, float* __restrict__ out, int BCc)
{
    int id = blockIdx.x * 256 + threadIdx.x;
    if (id >= BCc * 384) return;
    int b = id / 384, c = id - b * 384;
    float v = (anyv[b] > 0.f) ? ctx[id] : fs(fctx[c]);
    out[id] = fin(v);
}

__global__ void k_xtc(const float* __restrict__ tq, const int* __restrict__ qcode,
                      const float* __restrict__ Etr, const float* __restrict__ gst,
                      float* __restrict__ X, int BCc)
{
    int id = blockIdx.x * 256 + threadIdx.x;
    if (id >= BCc * 420) return;
    int b = id / 420, c = id - b * 420;
    float v;
    if (c < 384) v = tq[(size_t)b * 384 + c];
    else if (c < 416) v = fs(Etr[min(max(qcode[b], 0), 20) * 32 + (c - 384)]);
    else v = gst[(size_t)b * 4 + (c - 416)];
    X[id] = v;
}

__global__ void k_transfer(const float* __restrict__ nbr, const int* __restrict__ rsmask,
                           const int* __restrict__ rvalid, const float* __restrict__ swb,
                           const float* __restrict__ anyv, const float* __restrict__ sscale,
                           const float* __restrict__ fshift, float* __restrict__ out, int BCc)
{
    int id = blockIdx.x * 256 + threadIdx.x;
    if (id >= BCc * 6) return;
    int b = id / 6, s = id - b * 6;
    float res;
    if (anyv[b] <= 0.f) {
        res = fs(fshift[s]);
    } else {
        float wb = swb[b * 6 + s] * 0.1f;
        float mx = -1e30f;
        for (int k = 0; k < 32; k++) {
            int gk = b * 32 + k;
            bool m = (rvalid[gk] != 0) && (rsmask[gk * 6 + s] != 0);
            float wv = m ? (nbr[(size_t)gk * 30 + 28] + nbr[(size_t)gk * 30 + 29] * 0.5f + wb)
                         : -10000.f;
            mx = fmaxf(mx, wv);
        }
        float num = 0.f, den = 0.f;
        for (int k = 0; k < 32; k++) {
            int gk = b * 32 + k;
            bool m = (rvalid[gk] != 0) && (rsmask[gk * 6 + s] != 0);
            float wv = m ? (nbr[(size_t)gk * 30 + 28] + nbr[(size_t)gk * 30 + 29] * 0.5f + wb)
                         : -10000.f;
            float e = expf(wv - mx);
            num += e * nbr[(size_t)gk * 30 + s];
            den += e;
        }
        res = (num / den) * fs(sscale[s]);
    }
    out[id] = fin(res);
}

__global__ void k_trust(const float* __restrict__ tcp, const float* __restrict__ pst,
                        const float* __restrict__ Wtp1, const float* __restrict__ Wtp2,
                        const float* __restrict__ btp2, float* __restrict__ out, int BCc)
{
    int id = blockIdx.x * 256 + threadIdx.x;
    if (id >= BCc * 6) return;
    int b = id / 6, s = id - b * 6;
    const float* ps = pst + (size_t)b * 24 + s * 4;
    float acc = 0.f;
    for (int j = 0; j < 192; j++) {
        float pre = tcp[(size_t)b * 192 + j];
        pre += ps[0] * fs(Wtp1[(size_t)384 * 192 + j]);
        pre += ps[1] * fs(Wtp1[(size_t)385 * 192 + j]);
        pre += ps[2] * fs(Wtp1[(size_t)386 * 192 + j]);
        pre += ps[3] * fs(Wtp1[(size_t)387 * 192 + j]);
        acc += gelu_f(pre) * fs(Wtp2[j]);
    }
    float t = 1.f / (1.f + expf(-(acc + fs(btp2[0]))));
    out[id] = fin(t);
}

#define L1(total) <<<((total) + 255) / 256, 256, 0, stream>>>

extern "C" void kernel_launch(void* const* d_in, const int* in_sizes, int n_in,
                              void* d_out, int out_size, void* d_ws, size_t ws_size,
                              hipStream_t stream)
{
    float* out = (float*)d_out;

    static const int EXP[45] = {
        2097152, 4096, 24576, 24576, 786432, 786432, 131072, 131072, 131072, 126,
        196608, 384, 336, 11520, 384, 147456, 384, 147456, 384, 147456, 384,
        2304, 192, 1152, 6, 147456, 384, 147456, 384, 147456, 384, 2304, 6,
        672, 196608, 384, 161280, 384, 74496, 192, 192, 1, 6, 6, 384
    };
    if (n_in != 45) {
        fill_kernel L1(out_size)(out, out_size, 580.0f);
        return;
    }
    for (int i = 0; i < 45; i++) {
        if (in_sizes[i] != EXP[i]) {
            fill_kernel L1(out_size)(out, out_size, 600.0f + 4.0f * i);
            return;
        }
    }

    const float* i_qe    = (const float*)d_in[0];
    const int*   i_qcode = (const int*)d_in[1];
    const float* i_qobs  = (const float*)d_in[2];
    const float* i_qmask = (const float*)d_in[3];
    const float* i_rshift= (const float*)d_in[4];
    const int*   i_rsmask= (const int*)d_in[5];
    const int*   i_rcodes= (const int*)d_in[6];
    const float* i_rdist = (const float*)d_in[7];
    const int*   i_rvalid= (const int*)d_in[8];
    const float* i_rc    = (const float*)d_in[9];
    const float* i_Wqp   = (const float*)d_in[10];
    const float* i_bqp   = (const float*)d_in[11];
    const float* i_Eres  = (const float*)d_in[12];
    const float* i_Wnp   = (const float*)d_in[13];
    const float* i_bnp   = (const float*)d_in[14];
    const float* i_Waq   = (const float*)d_in[15];
    const float* i_baq   = (const float*)d_in[16];
    const float* i_Wak   = (const float*)d_in[17];
    const float* i_bak   = (const float*)d_in[18];
    const float* i_Wav   = (const float*)d_in[19];
    const float* i_bav   = (const float*)d_in[20];
    const float* i_Wss1  = (const float*)d_in[21];
    const float* i_bss1  = (const float*)d_in[22];
    const float* i_Wss2  = (const float*)d_in[23];
    const float* i_bss2  = (const float*)d_in[24];
    const float* i_Wcp1  = (const float*)d_in[25];
    const float* i_bcp1  = (const float*)d_in[26];
    const float* i_Wcp2  = (const float*)d_in[27];
    const float* i_bcp2  = (const float*)d_in[28];
    const float* i_Wsw1  = (const float*)d_in[29];
    const float* i_bsw1  = (const float*)d_in[30];
    const float* i_Wsw2  = (const float*)d_in[31];
    const float* i_bsw2  = (const float*)d_in[32];
    const float* i_Etr   = (const float*)d_in[33];
    const float* i_Wtq   = (const float*)d_in[34];
    const float* i_btq   = (const float*)d_in[35];
    const float* i_Wtc   = (const float*)d_in[36];
    const float* i_btc   = (const float*)d_in[37];
    const float* i_Wtp1  = (const float*)d_in[38];
    const float* i_btp1  = (const float*)d_in[39];
    const float* i_Wtp2  = (const float*)d_in[40];
    const float* i_btp2  = (const float*)d_in[41];
    const float* i_sscale= (const float*)d_in[42];
    const float* i_fshift= (const float*)d_in[43];
    const float* i_fctx  = (const float*)d_in[44];

    // ws-adaptive chunk (vms reuses the Qp buffer -> no layout growth vs prior)
    auto layoutBytes = [](int bc) -> size_t {
        size_t nb = (size_t)bc * 32, off = 0;
        auto a = [&](size_t nf) { off = (off + nf * 4 + 255) & ~(size_t)255; };
        a(nb * 30); a(nb * 12); a(nb * 6);
        a((size_t)bc * 384); a((size_t)bc * 384); a((size_t)bc * 384); a((size_t)bc * 384);
        a((size_t)bc * 384); a((size_t)bc * 384); a((size_t)bc * 384); a((size_t)bc * 384);
        a((size_t)bc * 192); a((size_t)bc * 420); a((size_t)bc * 2304);
        a((size_t)bc * 6); a((size_t)bc * 6); a((size_t)bc * 24); a((size_t)bc * 4); a(bc);
        return off;
    };
    const int cand[7] = {4096, 2048, 1024, 512, 256, 128, 64};
    int BCc = 64;
    for (int i = 0; i < 7; i++) {
        if (layoutBytes(cand[i]) <= ws_size) { BCc = cand[i]; break; }
    }
    const int NBc = BCc * 32;

    char* wsb = (char*)d_ws;
    size_t off = 0;
    auto alloc = [&](size_t nfloats) -> float* {
        float* p = (float*)(wsb + off);
        off = (off + nfloats * 4 + 255) & ~(size_t)255;
        return p;
    };
    float* nbr   = alloc((size_t)NBc * 30);
    float* sdiff = alloc((size_t)NBc * 12);
    float* bias_s= alloc((size_t)NBc * 6);
    float* qf    = alloc((size_t)BCc * 384);
    float* tqf   = alloc((size_t)BCc * 384);
    float* Qhf   = alloc((size_t)BCc * 384);
    float* attnf = alloc((size_t)BCc * 384);
    float* h1f   = alloc((size_t)BCc * 384);
    float* s1f   = alloc((size_t)BCc * 384);
    float* ctxf  = alloc((size_t)BCc * 384);
    float* tcf   = alloc((size_t)BCc * 384);
    float* tcpf  = alloc((size_t)BCc * 192);
    float* Xf    = alloc((size_t)BCc * 420);
    float* Qpf   = alloc((size_t)BCc * 2304);   // Qp, then reused as vms
    float* swbf  = alloc((size_t)BCc * 6);
    float* qkbf  = alloc((size_t)BCc * 6);
    float* pstf  = alloc((size_t)BCc * 24);
    float* gstf  = alloc((size_t)BCc * 4);
    float* anyf  = alloc((size_t)BCc);

    if (off > ws_size) {
        fill_kernel L1(out_size)(out, out_size, 1000.0f);
        return;
    }

    for (int c = 0; c < 4096 / BCc; c++) {
        const size_t B0 = (size_t)c * BCc;
        const dim3 g6(6, BCc / 64), g3(3, BCc / 64);
        const dim3 gqp(6, BCc / 64, 6), gao(6, BCc / 64);
        k_prep L1(NBc)(i_qobs + B0 * 6, i_qmask + B0 * 6, i_rshift + B0 * 192,
                       i_rsmask + B0 * 192, i_qcode + B0, i_rcodes + B0 * 32,
                       i_rdist + B0 * 32, i_rc, i_Eres, nbr, sdiff, NBc);
        k_stats L1(BCc)(nbr, i_rvalid + B0 * 32, pstf, gstf, anyf, BCc);
        k_mlpbias<<<BCc, 192, 0, stream>>>(sdiff, i_Wss1, i_bss1, i_Wss2, i_bss2, bias_s);
        k_gemm_mfma<1><<<g6, 256, 0, stream>>>(i_qe + B0 * 512, 512, i_Wqp, 384, i_bqp, qf, 384, 512);
        k_gemm_mfma<1><<<g6, 256, 0, stream>>>(i_qe + B0 * 512, 512, i_Wtq, 384, i_btq, tqf, 384, 512);
        k_gemm_mfma<0><<<g6, 256, 0, stream>>>(qf, 384, i_Waq, 384, i_baq, Qhf, 384, 384);
        k_qp_mfma<<<gqp, 256, 0, stream>>>(Qhf, i_Wak, Qpf);
        k_qkb L1(BCc * 6)(Qhf, i_bak, qkbf, BCc);
        k_attnblk<<<BCc, 384, 0, stream>>>(nbr, i_Wnp, i_bnp, Qpf, qkbf, bias_s,
                                           i_rvalid + B0 * 32, anyf);
        k_attnout_mfma<<<gao, 256, 0, stream>>>(Qpf, i_Wav, i_bav, attnf);
        k_gemm_mfma<1><<<g6, 256, 0, stream>>>(attnf, 384, i_Wcp1, 384, i_bcp1, h1f, 384, 384);
        k_gemm_mfma<0><<<g6, 256, 0, stream>>>(h1f, 384, i_Wcp2, 384, i_bcp2, ctxf, 384, 384);
        k_gemm_mfma<1><<<g6, 256, 0, stream>>>(attnf, 384, i_Wsw1, 384, i_bsw1, s1f, 384, 384);
        k_gemm<0> L1(BCc * 6)(s1f, 384, i_Wsw2, i_bsw2, swbf, BCc, 6, 384);
        k_ctxout L1(BCc * 384)(ctxf, anyf, i_fctx, out + B0 * 384, BCc);
        k_xtc L1(BCc * 420)(tqf, i_qcode + B0, i_Etr, gstf, Xf, BCc);
        k_gemm_mfma<1><<<g6, 256, 0, stream>>>(Xf, 420, i_Wtc, 384, i_btc, tcf, 384, 420);
        k_gemm_mfma<0><<<g3, 256, 0, stream>>>(tcf, 384, i_Wtp1, 192, i_btp1, tcpf, 192, 384);
        k_trust L1(BCc * 6)(tcpf, pstf, i_Wtp1, i_Wtp2, i_btp2,
                            out + (size_t)4096 * 390 + B0 * 6, BCc);
        k_transfer L1(BCc * 6)(nbr, i_rsmask + B0 * 192, i_rvalid + B0 * 32, swbf, anyf,
                               i_sscale, i_fshift, out + (size_t)4096 * 384 + B0 * 6, BCc);
    }
}

// Round 3
// 877.567 us; speedup vs baseline: 2.0018x; 1.4313x over previous
//
#include <hip/hip_runtime.h>

typedef unsigned short u16;
typedef __attribute__((ext_vector_type(8))) short bf16x8;
typedef __attribute__((ext_vector_type(4))) float f32x4;

__device__ __forceinline__ float fs(float f) {
    return (f == f && fabsf(f) < 1e30f) ? f : 0.f;
}
__device__ __forceinline__ float fin(float v) {
    return (v == v && fabsf(v) < 1e30f) ? v : 555.0f;
}
__device__ __forceinline__ u16 f2b(float f) {
    union { float f; unsigned int i; } w; w.f = f;
    unsigned int r = w.i + 0x7FFFu + ((w.i >> 16) & 1u);
    return (u16)(r >> 16);
}
__device__ __forceinline__ float gelu_f(float x) {
    return 0.5f * x * (1.0f + erff(x * 0.70710678118654752440f));
}

__global__ void fill_kernel(float* __restrict__ out, int n, float val) {
    int i = blockIdx.x * 256 + threadIdx.x;
    if (i < n) out[i] = val;
}

// flat f32 -> bf16 convert (sanitizing)
__global__ void k_cvt(const float* __restrict__ in, u16* __restrict__ out, int n) {
    int i = blockIdx.x * 256 + threadIdx.x;
    if (i < n) out[i] = f2b(fs(in[i]));
}

// W (K x N, f32) -> WT (N x Kp, bf16), zero-padded for k >= K
__global__ void k_cvtT(const float* __restrict__ W, u16* __restrict__ WT,
                       int K, int N, int Kp, int total) {
    int id = blockIdx.x * 256 + threadIdx.x;
    if (id >= total) return;
    int n = id / Kp, k = id - n * Kp;
    WT[id] = (k < K) ? f2b(fs(W[(size_t)k * N + n])) : (u16)0;
}

// nbr row (30) + sdiff row (12), one thread per (b,k)
__global__ void k_prep(const float* __restrict__ qobs, const float* __restrict__ qmask,
                       const float* __restrict__ rshift, const int* __restrict__ rsmask,
                       const int* __restrict__ qcode, const int* __restrict__ rcodes,
                       const float* __restrict__ rdist, const float* __restrict__ rc_table,
                       const float* __restrict__ E_res,
                       float* __restrict__ nbr, float* __restrict__ sdiff, int NBc)
{
    int gk = blockIdx.x * 256 + threadIdx.x;
    if (gk >= NBc) return;
    int b = gk >> 5;
    int qc = qcode[b], rc = rcodes[gk];
    int qi = min(max(qc, 0), 20), ri = min(max(rc, 0), 20);
    float dist = fs(rdist[gk]);
    float same = (rc == qc) ? 1.f : 0.f;
    float* nr = nbr + (size_t)gk * 30;
    float* sd = sdiff + (size_t)gk * 12;
    for (int s = 0; s < 6; s++) {
        float rs = fs(rshift[gk * 6 + s]);
        bool m = rsmask[gk * 6 + s] != 0;
        float rq = rc_table[qi * 6 + s];
        float rr = rc_table[ri * 6 + s];
        bool rcv = (rq == rq) && (rr == rr) && fabsf(rq) < 1e30f && fabsf(rr) < 1e30f;
        float sh = (m && rcv) ? (rq + rs - rr) : rs;
        nr[s] = sh;
        nr[6 + s] = m ? 1.f : 0.f;
        float qm = fs(qmask[b * 6 + s]);
        sd[s] = (fs(qobs[b * 6 + s]) - sh) * qm;
        sd[6 + s] = qm;
    }
    for (int j = 0; j < 16; j++) nr[12 + j] = fs(E_res[ri * 16 + j]);
    nr[28] = dist;
    nr[29] = same;
}

// per-(b,s) stats
__global__ void k_statsS(const float* __restrict__ nbr, const int* __restrict__ rvalid,
                         float* __restrict__ pst, int BCc)
{
    int id = blockIdx.x * 256 + threadIdx.x;
    if (id >= BCc * 6) return;
    int b = id / 6, s = id - b * 6;
    float cnt = 0.f, msum = 0.f, mdist = 0.f, mst = 0.f;
    for (int k = 0; k < 32; k++) {
        const float* nr = nbr + (size_t)(b * 32 + k) * 30;
        float vf = (rvalid[b * 32 + k] != 0) ? 1.f : 0.f;
        float vm = vf * nr[6 + s];
        cnt += vm; msum += nr[s] * vm; mdist += nr[28] * vm; mst += nr[29] * vm;
    }
    float inv = 1.f / (cnt + 1e-8f);
    float mean = msum * inv;
    float var = 0.f;
    for (int k = 0; k < 32; k++) {
        const float* nr = nbr + (size_t)(b * 32 + k) * 30;
        float vf = (rvalid[b * 32 + k] != 0) ? 1.f : 0.f;
        float vm = vf * nr[6 + s];
        float dv = nr[s] - mean;
        var += dv * dv * vm;
    }
    var *= inv;
    float* p = pst + (size_t)b * 24 + s * 4;
    p[0] = cnt * (1.f / 32.f);
    p[1] = fminf(fmaxf(log1pf(var), 0.f), 5.f) * 0.2f;
    p[2] = mdist * inv;
    p[3] = mst * inv;
}

// per-b global stats
__global__ void k_statsG(const float* __restrict__ nbr, const int* __restrict__ rvalid,
                         float* __restrict__ gst, float* __restrict__ anyv, int BCc)
{
    int b = blockIdx.x * 256 + threadIdx.x;
    if (b >= BCc) return;
    float svf = 0.f, sdm = 0.f, mdm = -1e30f, ssm = 0.f;
    for (int k = 0; k < 32; k++) {
        const float* nr = nbr + (size_t)(b * 32 + k) * 30;
        float vf = (rvalid[b * 32 + k] != 0) ? 1.f : 0.f;
        float dm = vf * nr[28];
        svf += vf; sdm += dm; mdm = fmaxf(mdm, dm); ssm += vf * nr[29];
    }
    float* g = gst + (size_t)b * 4;
    g[0] = sdm / (svf + 1e-8f);
    g[1] = mdm;
    g[2] = svf * (1.f / 32.f);
    g[3] = ssm * (1.f / 32.f);
    anyv[b] = (svf > 0.f) ? 1.f : 0.f;
}

// scalar GEMM (small-N): C = act(A@B + bias)
template <int ACT>
__global__ void k_gemm(const float* __restrict__ A, int lda,
                       const float* __restrict__ B, const float* __restrict__ bias,
                       float* __restrict__ C, int M, int N, int K)
{
    int id = blockIdx.x * 256 + threadIdx.x;
    if (id >= M * N) return;
    int m = id / N, n = id - m * N;
    float acc = bias ? fs(bias[n]) : 0.f;
    const float* Ap = A + (size_t)m * lda;
    for (int k = 0; k < K; k++) acc += Ap[k] * fs(B[(size_t)k * N + n]);
    C[id] = (ACT == 1) ? gelu_f(acc) : acc;
}

// bf16 MFMA GEMM body: C = act(A @ BT^T + bias).
// A: M x K bf16 row-major (lda). BT: N x K bf16 row-major (ldb).
// Requires K % 64 == 0, tile 64x64, 256 threads.
template <int ACT, bool OUTF, bool OUTB>
__device__ __forceinline__ void gemm_body(
    const u16* __restrict__ A, int lda,
    const u16* __restrict__ BT, int ldb,
    const float* __restrict__ bias,
    float* __restrict__ Cf, u16* __restrict__ Cb, int ldc,
    int K, int m0, int n0)
{
    __shared__ u16 As[64 * 72];
    __shared__ u16 Bs[64 * 72];
    const int t = threadIdx.x;
    const int lane = t & 63, wave = t >> 6;
    const int wm = (wave & 1) << 5, wn = (wave >> 1) << 5;
    const int frm = lane & 15, frq = lane >> 4;
    const int r0 = t >> 3, c0 = (t & 7) << 3;
    const f32x4 z = {0.f, 0.f, 0.f, 0.f};
    f32x4 acc[2][2] = {{z, z}, {z, z}};
    for (int k0 = 0; k0 < K; k0 += 64) {
        *(bf16x8*)&As[r0 * 72 + c0]        = *(const bf16x8*)&A[(size_t)(m0 + r0) * lda + k0 + c0];
        *(bf16x8*)&As[(r0 + 32) * 72 + c0] = *(const bf16x8*)&A[(size_t)(m0 + r0 + 32) * lda + k0 + c0];
        *(bf16x8*)&Bs[r0 * 72 + c0]        = *(const bf16x8*)&BT[(size_t)(n0 + r0) * ldb + k0 + c0];
        *(bf16x8*)&Bs[(r0 + 32) * 72 + c0] = *(const bf16x8*)&BT[(size_t)(n0 + r0 + 32) * ldb + k0 + c0];
        __syncthreads();
#pragma unroll
        for (int kk = 0; kk < 2; kk++) {
            const int fo = (kk << 5) + (frq << 3);
            bf16x8 a0 = *(const bf16x8*)&As[(wm + frm) * 72 + fo];
            bf16x8 a1 = *(const bf16x8*)&As[(wm + 16 + frm) * 72 + fo];
            bf16x8 b0 = *(const bf16x8*)&Bs[(wn + frm) * 72 + fo];
            bf16x8 b1 = *(const bf16x8*)&Bs[(wn + 16 + frm) * 72 + fo];
            acc[0][0] = __builtin_amdgcn_mfma_f32_16x16x32_bf16(a0, b0, acc[0][0], 0, 0, 0);
            acc[0][1] = __builtin_amdgcn_mfma_f32_16x16x32_bf16(a0, b1, acc[0][1], 0, 0, 0);
            acc[1][0] = __builtin_amdgcn_mfma_f32_16x16x32_bf16(a1, b0, acc[1][0], 0, 0, 0);
            acc[1][1] = __builtin_amdgcn_mfma_f32_16x16x32_bf16(a1, b1, acc[1][1], 0, 0, 0);
        }
        __syncthreads();
    }
#pragma unroll
    for (int mi = 0; mi < 2; mi++) {
#pragma unroll
        for (int ni = 0; ni < 2; ni++) {
            int col = n0 + wn + (ni << 4) + frm;
            float bv = bias ? fs(bias[col]) : 0.f;
#pragma unroll
            for (int r = 0; r < 4; r++) {
                int row = m0 + wm + (mi << 4) + (frq << 2) + r;
                float v = acc[mi][ni][r] + bv;
                if (ACT == 1) v = gelu_f(v);
                if (OUTF) Cf[(size_t)row * ldc + col] = v;
                if (OUTB) Cb[(size_t)row * ldc + col] = f2b(v);
            }
        }
    }
}

template <int ACT, bool OUTF, bool OUTB>
__global__ __launch_bounds__(256) void k_gemm_bb(
    const u16* __restrict__ A, int lda, const u16* __restrict__ BT, int ldb,
    const float* __restrict__ bias, float* __restrict__ Cf, u16* __restrict__ Cb,
    int ldc, int K)
{
    gemm_body<ACT, OUTF, OUTB>(A, lda, BT, ldb, bias, Cf, Cb, ldc, K,
                               blockIdx.y << 6, blockIdx.x << 6);
}

// Qp[b, hd*384+j] = sum_d Qh[b, hd*64+d] * Wak[j, hd*64+d]
__global__ __launch_bounds__(256) void k_qp_bb(
    const u16* __restrict__ Qhb, const u16* __restrict__ WakB, float* __restrict__ Qp)
{
    int hd = blockIdx.z;
    gemm_body<0, true, false>(Qhb + hd * 64, 384, WakB + hd * 64, 384, nullptr,
                              Qp + hd * 384, nullptr, 2304, 64,
                              blockIdx.y << 6, blockIdx.x << 6);
}

// attn[b, hd*64+n] = sum_j vms[b, hd*384+j] * WavT[hd*64+n, j] + bav[hd*64+n]
// vms rows are bf16 packed in the FRONT HALF of each f32 Qp row: u16 row stride 4608.
__global__ __launch_bounds__(256) void k_attnout_bb(
    const u16* __restrict__ vmsb, const u16* __restrict__ WavT,
    const float* __restrict__ bav, u16* __restrict__ attnb)
{
    int hd = blockIdx.x;
    gemm_body<0, false, true>(vmsb + hd * 384, 4608, WavT + (size_t)hd * 64 * 384, 384,
                              bav + hd * 64, nullptr, attnb + hd * 64, 384, 384,
                              blockIdx.y << 6, 0);
}

// fused score-bias MLP: one block per b (192 threads); hid kept in LDS
__global__ __launch_bounds__(192) void k_mlpbias(
    const float* __restrict__ sdiff, const float* __restrict__ Wss1,
    const float* __restrict__ bss1, const float* __restrict__ Wss2,
    const float* __restrict__ bss2, float* __restrict__ bias_s)
{
    __shared__ float sdS[32 * 12];
    __shared__ float hidS[32 * 193];
    const int b = blockIdx.x;
    const int t = threadIdx.x;
    for (int i = t; i < 384; i += 192) sdS[i] = sdiff[(size_t)b * 384 + i];
    __syncthreads();
    {
        float w[12];
#pragma unroll
        for (int j = 0; j < 12; j++) w[j] = fs(Wss1[j * 192 + t]);
        float b1 = fs(bss1[t]);
        for (int k = 0; k < 32; k++) {
            float acc = b1;
#pragma unroll
            for (int j = 0; j < 12; j++) acc += sdS[k * 12 + j] * w[j];
            hidS[k * 193 + t] = gelu_f(acc);
        }
    }
    __syncthreads();
    {
        int k = t / 6, s = t - k * 6;
        float acc = fs(bss2[s]);
        for (int n = 0; n < 192; n++) acc += hidS[k * 193 + n] * fs(Wss2[n * 6 + s]);
        bias_s[(size_t)(b * 32 + k) * 6 + s] = acc;
    }
}

__global__ void k_qkb(const float* __restrict__ Qh, const float* __restrict__ bak,
                      float* __restrict__ qkb, int BCc)
{
    int id = blockIdx.x * 256 + threadIdx.x;
    if (id >= BCc * 6) return;
    int b = id / 6, h = id - b * 6;
    float acc = 0.f;
    for (int d = 0; d < 64; d++)
        acc += Qh[(size_t)b * 384 + h * 64 + d] * fs(bak[h * 64 + d]);
    qkb[id] = acc;
}

// attention core: kv + scores + softmax + weighted-sum. Writes vms as bf16
// into the FRONT HALF of this block's own f32 Qp row (u16 stride 4608) --
// race-free: each block reads its full f32 row into LDS before overwriting.
__global__ __launch_bounds__(384) void k_attnblk(
    const float* __restrict__ nbr, const float* __restrict__ Wnp,
    const float* __restrict__ bnp, float* Qp /* in: Qp f32, out: vms bf16 */,
    const float* __restrict__ qkb, const float* __restrict__ bias_s,
    const int* __restrict__ rvalid, const float* __restrict__ anyv)
{
    __shared__ float kvs[32 * 385];   // 49280 B
    __shared__ float qS[2304];        // 9216 B
    __shared__ float wsx[192];        // 768 B
    const int b = blockIdx.x;
    const int t = threadIdx.x;
    for (int i = t; i < 2304; i += 384) qS[i] = Qp[(size_t)b * 2304 + i];
    {   // stage A: kv[k][t] = gelu(sum_j nbr[b,k,j]*Wnp[j][t] + bnp[t])
        float w[30];
#pragma unroll
        for (int j = 0; j < 30; j++) w[j] = fs(Wnp[j * 384 + t]);
        float bb = fs(bnp[t]);
        const float* nr = nbr + (size_t)b * 960;   // block-uniform -> s_load
        for (int k = 0; k < 32; k++) {
            float acc = bb;
#pragma unroll
            for (int j = 0; j < 30; j++) acc += nr[k * 30 + j] * w[j];
            kvs[k * 385 + t] = gelu_f(acc);
        }
    }
    __syncthreads();
    {   // stage B: scores + wave-parallel softmax (wave = head, lane pairs split dot)
        const int p = t >> 1, half = t & 1;
        const int h = p >> 5, k = p & 31;
        const float* kr = &kvs[k * 385 + half * 192];
        const float* qr = &qS[h * 384 + half * 192];
        float acc = 0.f;
#pragma unroll 8
        for (int j = 0; j < 192; j++) acc += kr[j] * qr[j];
        acc += __shfl_xor(acc, 1);
        float s = (acc + qkb[b * 6 + h]) * 0.125f + bias_s[(size_t)(b * 32 + k) * 6 + h];
        bool ve = (rvalid[b * 32 + k] != 0) || (anyv[b] == 0.f && k == 0);
        s = ve ? s : -10000.f;
        float mx = s;
        mx = fmaxf(mx, __shfl_xor(mx, 2));
        mx = fmaxf(mx, __shfl_xor(mx, 4));
        mx = fmaxf(mx, __shfl_xor(mx, 8));
        mx = fmaxf(mx, __shfl_xor(mx, 16));
        mx = fmaxf(mx, __shfl_xor(mx, 32));
        float e = expf(s - mx);
        float sum = e;
        sum += __shfl_xor(sum, 2);
        sum += __shfl_xor(sum, 4);
        sum += __shfl_xor(sum, 8);
        sum += __shfl_xor(sum, 16);
        sum += __shfl_xor(sum, 32);
        if (half == 0) wsx[h * 32 + k] = e / sum;
    }
    __syncthreads();
    {   // stage C: vms[h][t] = sum_k w[h][k]*kv[k][t] -> bf16, u16 row stride 4608
        float a0 = 0.f, a1 = 0.f, a2 = 0.f, a3 = 0.f, a4 = 0.f, a5 = 0.f;
        for (int k = 0; k < 32; k++) {
            float kvv = kvs[k * 385 + t];
            a0 += wsx[k] * kvv;
            a1 += wsx[32 + k] * kvv;
            a2 += wsx[64 + k] * kvv;
            a3 += wsx[96 + k] * kvv;
            a4 += wsx[128 + k] * kvv;
            a5 += wsx[160 + k] * kvv;
        }
        u16* vp = (u16*)Qp + (size_t)b * 4608;
        vp[t] = f2b(a0);
        vp[384 + t] = f2b(a1);
        vp[768 + t] = f2b(a2);
        vp[1152 + t] = f2b(a3);
        vp[1536 + t] = f2b(a4);
        vp[1920 + t] = f2b(a5);
    }
}

__global__ void k_ctxout(const float* __restrict__ ctx, const float* __restrict__ anyv,
                         const float* __restrict__ fctx, float* __restrict__ out, int BCc)
{
    int id = blockIdx.x * 256 + threadIdx.x;
    if (id >= BCc * 384) return;
    int b = id / 384, c = id - b * 384;
    float v = (anyv[b] > 0.f) ? ctx[id] : fs(fctx[c]);
    out[id] = fin(v);
}

// assemble trust-input X as bf16, row stride 448 (zero pad 420..447)
__global__ void k_xtc_b(const float* __restrict__ tqf, const int* __restrict__ qcode,
                        const float* __restrict__ Etr, const float* __restrict__ gst,
                        u16* __restrict__ Xb, int BCc)
{
    int id = blockIdx.x * 256 + threadIdx.x;
    if (id >= BCc * 448) return;
    int b = id / 448, c = id - b * 448;
    float v;
    if (c < 384) v = tqf[(size_t)b * 384 + c];
    else if (c < 416) v = fs(Etr[min(max(qcode[b], 0), 20) * 32 + (c - 384)]);
    else if (c < 420) v = gst[(size_t)b * 4 + (c - 416)];
    else v = 0.f;
    Xb[id] = f2b(v);
}

__global__ void k_transfer(const float* __restrict__ nbr, const int* __restrict__ rsmask,
                           const int* __restrict__ rvalid, const float* __restrict__ swb,
                           const float* __restrict__ anyv, const float* __restrict__ sscale,
                           const float* __restrict__ fshift, float* __restrict__ out, int BCc)
{
    int id = blockIdx.x * 256 + threadIdx.x;
    if (id >= BCc * 6) return;
    int b = id / 6, s = id - b * 6;
    float res;
    if (anyv[b] <= 0.f) {
        res = fs(fshift[s]);
    } else {
        float wb = swb[b * 6 + s] * 0.1f;
        float mx = -1e30f;
        for (int k = 0; k < 32; k++) {
            int gk = b * 32 + k;
            bool m = (rvalid[gk] != 0) && (rsmask[gk * 6 + s] != 0);
            float wv = m ? (nbr[(size_t)gk * 30 + 28] + nbr[(size_t)gk * 30 + 29] * 0.5f + wb)
                         : -10000.f;
            mx = fmaxf(mx, wv);
        }
        float num = 0.f, den = 0.f;
        for (int k = 0; k < 32; k++) {
            int gk = b * 32 + k;
            bool m = (rvalid[gk] != 0) && (rsmask[gk * 6 + s] != 0);
            float wv = m ? (nbr[(size_t)gk * 30 + 28] + nbr[(size_t)gk * 30 + 29] * 0.5f + wb)
                         : -10000.f;
            float e = expf(wv - mx);
            num += e * nbr[(size_t)gk * 30 + s];
            den += e;
        }
        res = (num / den) * fs(sscale[s]);
    }
    out[id] = fin(res);
}

__global__ void k_trust(const float* __restrict__ tcp, const float* __restrict__ pst,
                        const float* __restrict__ Wtp1, const float* __restrict__ Wtp2,
                        const float* __restrict__ btp2, float* __restrict__ out, int BCc)
{
    int id = blockIdx.x * 256 + threadIdx.x;
    if (id >= BCc * 6) return;
    int b = id / 6, s = id - b * 6;
    const float* ps = pst + (size_t)b * 24 + s * 4;
    float acc = 0.f;
    for (int j = 0; j < 192; j++) {
        float pre = tcp[(size_t)b * 192 + j];
        pre += ps[0] * fs(Wtp1[(size_t)384 * 192 + j]);
        pre += ps[1] * fs(Wtp1[(size_t)385 * 192 + j]);
        pre += ps[2] * fs(Wtp1[(size_t)386 * 192 + j]);
        pre += ps[3] * fs(Wtp1[(size_t)387 * 192 + j]);
        acc += gelu_f(pre) * fs(Wtp2[j]);
    }
    float t = 1.f / (1.f + expf(-(acc + fs(btp2[0]))));
    out[id] = fin(t);
}

#define L1(total) <<<((total) + 255) / 256, 256, 0, stream>>>

extern "C" void kernel_launch(void* const* d_in, const int* in_sizes, int n_in,
                              void* d_out, int out_size, void* d_ws, size_t ws_size,
                              hipStream_t stream)
{
    float* out = (float*)d_out;

    static const int EXP[45] = {
        2097152, 4096, 24576, 24576, 786432, 786432, 131072, 131072, 131072, 126,
        196608, 384, 336, 11520, 384, 147456, 384, 147456, 384, 147456, 384,
        2304, 192, 1152, 6, 147456, 384, 147456, 384, 147456, 384, 2304, 6,
        672, 196608, 384, 161280, 384, 74496, 192, 192, 1, 6, 6, 384
    };
    if (n_in != 45) {
        fill_kernel L1(out_size)(out, out_size, 580.0f);
        return;
    }
    for (int i = 0; i < 45; i++) {
        if (in_sizes[i] != EXP[i]) {
            fill_kernel L1(out_size)(out, out_size, 600.0f + 4.0f * i);
            return;
        }
    }

    const float* i_qe    = (const float*)d_in[0];
    const int*   i_qcode = (const int*)d_in[1];
    const float* i_qobs  = (const float*)d_in[2];
    const float* i_qmask = (const float*)d_in[3];
    const float* i_rshift= (const float*)d_in[4];
    const int*   i_rsmask= (const int*)d_in[5];
    const int*   i_rcodes= (const int*)d_in[6];
    const float* i_rdist = (const float*)d_in[7];
    const int*   i_rvalid= (const int*)d_in[8];
    const float* i_rc    = (const float*)d_in[9];
    const float* i_Wqp   = (const float*)d_in[10];
    const float* i_bqp   = (const float*)d_in[11];
    const float* i_Eres  = (const float*)d_in[12];
    const float* i_Wnp   = (const float*)d_in[13];
    const float* i_bnp   = (const float*)d_in[14];
    const float* i_Waq   = (const float*)d_in[15];
    const float* i_baq   = (const float*)d_in[16];
    const float* i_Wak   = (const float*)d_in[17];
    const float* i_bak   = (const float*)d_in[18];
    const float* i_Wav   = (const float*)d_in[19];
    const float* i_bav   = (const float*)d_in[20];
    const float* i_Wss1  = (const float*)d_in[21];
    const float* i_bss1  = (const float*)d_in[22];
    const float* i_Wss2  = (const float*)d_in[23];
    const float* i_bss2  = (const float*)d_in[24];
    const float* i_Wcp1  = (const float*)d_in[25];
    const float* i_bcp1  = (const float*)d_in[26];
    const float* i_Wcp2  = (const float*)d_in[27];
    const float* i_bcp2  = (const float*)d_in[28];
    const float* i_Wsw1  = (const float*)d_in[29];
    const float* i_bsw1  = (const float*)d_in[30];
    const float* i_Wsw2  = (const float*)d_in[31];
    const float* i_bsw2  = (const float*)d_in[32];
    const float* i_Etr   = (const float*)d_in[33];
    const float* i_Wtq   = (const float*)d_in[34];
    const float* i_btq   = (const float*)d_in[35];
    const float* i_Wtc   = (const float*)d_in[36];
    const float* i_btc   = (const float*)d_in[37];
    const float* i_Wtp1  = (const float*)d_in[38];
    const float* i_btp1  = (const float*)d_in[39];
    const float* i_Wtp2  = (const float*)d_in[40];
    const float* i_btp2  = (const float*)d_in[41];
    const float* i_sscale= (const float*)d_in[42];
    const float* i_fshift= (const float*)d_in[43];
    const float* i_fctx  = (const float*)d_in[44];

    auto layoutBytes = [](int bc) -> size_t {
        auto al = [](size_t x) { return (x + 255) & ~(size_t)255; };
        size_t off = 0;
        // fixed: qeb + bf16 weights
        off += al(2097152ull * 2);
        off += al(196608ull * 2) * 2;
        off += al(147456ull * 2) * 6;
        off += al(172032ull * 2);
        off += al(73728ull * 2);
        // per-chunk
        size_t nb = (size_t)bc * 32;
        off += al(nb * 30 * 4) + al(nb * 12 * 4) + al(nb * 6 * 4);
        off += al((size_t)bc * 384 * 4) * 4;   // tqf, Qhf, s1f, ctxf
        off += al((size_t)bc * 192 * 4);       // tcpf
        off += al((size_t)bc * 2304 * 4);      // Qpf
        off += al((size_t)bc * 384 * 2) * 5;   // qfb, Qhb, attnb, h1b, tcb
        off += al((size_t)bc * 448 * 2);       // Xfb
        off += al((size_t)bc * 6 * 4) * 2 + al((size_t)bc * 24 * 4)
             + al((size_t)bc * 4 * 4) + al((size_t)bc * 4);
        return off;
    };
    const int cand[7] = {4096, 2048, 1024, 512, 256, 128, 64};
    int BCc = 64;
    for (int i = 0; i < 7; i++) {
        if (layoutBytes(cand[i]) <= ws_size) { BCc = cand[i]; break; }
    }
    const int NBc = BCc * 32;

    char* wsb = (char*)d_ws;
    size_t off = 0;
    auto allocB = [&](size_t bytes) -> void* {
        void* p = (void*)(wsb + off);
        off = (off + bytes + 255) & ~(size_t)255;
        return p;
    };
    // fixed
    u16* qeb    = (u16*)allocB(2097152ull * 2);
    u16* WqpT   = (u16*)allocB(196608ull * 2);
    u16* WtqT   = (u16*)allocB(196608ull * 2);
    u16* WaqT   = (u16*)allocB(147456ull * 2);
    u16* WakB   = (u16*)allocB(147456ull * 2);
    u16* WavT   = (u16*)allocB(147456ull * 2);
    u16* Wcp1T  = (u16*)allocB(147456ull * 2);
    u16* Wcp2T  = (u16*)allocB(147456ull * 2);
    u16* Wsw1T  = (u16*)allocB(147456ull * 2);
    u16* WtcT   = (u16*)allocB(172032ull * 2);
    u16* Wtp1T  = (u16*)allocB(73728ull * 2);
    // per-chunk
    float* nbr   = (float*)allocB((size_t)NBc * 30 * 4);
    float* sdiff = (float*)allocB((size_t)NBc * 12 * 4);
    float* bias_s= (float*)allocB((size_t)NBc * 6 * 4);
    float* tqf   = (float*)allocB((size_t)BCc * 384 * 4);
    float* Qhf   = (float*)allocB((size_t)BCc * 384 * 4);
    float* s1f   = (float*)allocB((size_t)BCc * 384 * 4);
    float* ctxf  = (float*)allocB((size_t)BCc * 384 * 4);
    float* tcpf  = (float*)allocB((size_t)BCc * 192 * 4);
    float* Qpf   = (float*)allocB((size_t)BCc * 2304 * 4);  // Qp f32, then vms bf16
    u16*   qfb   = (u16*)allocB((size_t)BCc * 384 * 2);
    u16*   Qhb   = (u16*)allocB((size_t)BCc * 384 * 2);
    u16*   attnb = (u16*)allocB((size_t)BCc * 384 * 2);
    u16*   h1b   = (u16*)allocB((size_t)BCc * 384 * 2);
    u16*   tcb   = (u16*)allocB((size_t)BCc * 384 * 2);
    u16*   Xfb   = (u16*)allocB((size_t)BCc * 448 * 2);
    float* swbf  = (float*)allocB((size_t)BCc * 6 * 4);
    float* qkbf  = (float*)allocB((size_t)BCc * 6 * 4);
    float* pstf  = (float*)allocB((size_t)BCc * 24 * 4);
    float* gstf  = (float*)allocB((size_t)BCc * 4 * 4);
    float* anyf  = (float*)allocB((size_t)BCc * 4);

    if (off > ws_size) {
        fill_kernel L1(out_size)(out, out_size, 1000.0f);
        return;
    }

    // one-time conversions (bit-identical rounding to previous per-GEMM f2b(fs()))
    k_cvt L1(2097152)(i_qe, qeb, 2097152);
    k_cvtT L1(196608)(i_Wqp, WqpT, 512, 384, 512, 196608);
    k_cvtT L1(196608)(i_Wtq, WtqT, 512, 384, 512, 196608);
    k_cvtT L1(147456)(i_Waq, WaqT, 384, 384, 384, 147456);
    k_cvt L1(147456)(i_Wak, WakB, 147456);
    k_cvtT L1(147456)(i_Wav, WavT, 384, 384, 384, 147456);
    k_cvtT L1(147456)(i_Wcp1, Wcp1T, 384, 384, 384, 147456);
    k_cvtT L1(147456)(i_Wcp2, Wcp2T, 384, 384, 384, 147456);
    k_cvtT L1(147456)(i_Wsw1, Wsw1T, 384, 384, 384, 147456);
    k_cvtT L1(172032)(i_Wtc, WtcT, 420, 384, 448, 172032);
    k_cvtT L1(73728)(i_Wtp1, Wtp1T, 384, 192, 384, 73728);

    for (int c = 0; c < 4096 / BCc; c++) {
        const size_t B0 = (size_t)c * BCc;
        const dim3 g6(6, BCc / 64), g3(3, BCc / 64);
        const dim3 gqp(6, BCc / 64, 6), gao(6, BCc / 64);
        k_prep L1(NBc)(i_qobs + B0 * 6, i_qmask + B0 * 6, i_rshift + B0 * 192,
                       i_rsmask + B0 * 192, i_qcode + B0, i_rcodes + B0 * 32,
                       i_rdist + B0 * 32, i_rc, i_Eres, nbr, sdiff, NBc);
        k_statsS L1(BCc * 6)(nbr, i_rvalid + B0 * 32, pstf, BCc);
        k_statsG L1(BCc)(nbr, i_rvalid + B0 * 32, gstf, anyf, BCc);
        k_mlpbias<<<BCc, 192, 0, stream>>>(sdiff, i_Wss1, i_bss1, i_Wss2, i_bss2, bias_s);
        k_gemm_bb<1, false, true><<<g6, 256, 0, stream>>>(
            qeb + B0 * 512, 512, WqpT, 512, i_bqp, nullptr, qfb, 384, 512);
        k_gemm_bb<1, true, false><<<g6, 256, 0, stream>>>(
            qeb + B0 * 512, 512, WtqT, 512, i_btq, tqf, nullptr, 384, 512);
        k_gemm_bb<0, true, true><<<g6, 256, 0, stream>>>(
            qfb, 384, WaqT, 384, i_baq, Qhf, Qhb, 384, 384);
        k_qp_bb<<<gqp, 256, 0, stream>>>(Qhb, WakB, Qpf);
        k_qkb L1(BCc * 6)(Qhf, i_bak, qkbf, BCc);
        k_attnblk<<<BCc, 384, 0, stream>>>(nbr, i_Wnp, i_bnp, Qpf, qkbf, bias_s,
                                           i_rvalid + B0 * 32, anyf);
        k_attnout_bb<<<gao, 256, 0, stream>>>((const u16*)Qpf, WavT, i_bav, attnb);
        k_gemm_bb<1, false, true><<<g6, 256, 0, stream>>>(
            attnb, 384, Wcp1T, 384, i_bcp1, nullptr, h1b, 384, 384);
        k_gemm_bb<0, true, false><<<g6, 256, 0, stream>>>(
            h1b, 384, Wcp2T, 384, i_bcp2, ctxf, nullptr, 384, 384);
        k_gemm_bb<1, true, false><<<g6, 256, 0, stream>>>(
            attnb, 384, Wsw1T, 384, i_bsw1, s1f, nullptr, 384, 384);
        k_gemm<0> L1(BCc * 6)(s1f, 384, i_Wsw2, i_bsw2, swbf, BCc, 6, 384);
        k_ctxout L1(BCc * 384)(ctxf, anyf, i_fctx, out + B0 * 384, BCc);
        k_xtc_b L1(BCc * 448)(tqf, i_qcode + B0, i_Etr, gstf, Xfb, BCc);
        k_gemm_bb<1, false, true><<<g6, 256, 0, stream>>>(
            Xfb, 448, WtcT, 448, i_btc, nullptr, tcb, 384, 448);
        k_gemm_bb<0, true, false><<<g3, 256, 0, stream>>>(
            tcb, 384, Wtp1T, 384, i_btp1, tcpf, nullptr, 192, 384);
        k_trust L1(BCc * 6)(tcpf, pstf, i_Wtp1, i_Wtp2, i_btp2,
                            out + (size_t)4096 * 390 + B0 * 6, BCc);
        k_transfer L1(BCc * 6)(nbr, i_rsmask + B0 * 192, i_rvalid + B0 * 32, swbf, anyf,
                               i_sscale, i_fshift, out + (size_t)4096 * 384 + B0 * 6, BCc);
    }
}

// Round 6
// 556.539 us; speedup vs baseline: 3.1565x; 1.5768x over previous
//
#include <hip/hip_runtime.h>

typedef unsigned short u16;
typedef unsigned int u32;
typedef __attribute__((ext_vector_type(8))) short bf16x8;
typedef __attribute__((ext_vector_type(4))) float f32x4;

__device__ __forceinline__ float fs(float f) {
    return (f == f && fabsf(f) < 1e30f) ? f : 0.f;
}
__device__ __forceinline__ float fin(float v) {
    return (v == v && fabsf(v) < 1e30f) ? v : 555.0f;
}
__device__ __forceinline__ u16 f2b(float f) {
    union { float f; unsigned int i; } w; w.f = f;
    unsigned int r = w.i + 0x7FFFu + ((w.i >> 16) & 1u);
    return (u16)(r >> 16);
}
__device__ __forceinline__ float b2f(u16 b) {
    union { unsigned int i; float f; } w; w.i = ((unsigned int)b) << 16;
    return w.f;
}
__device__ __forceinline__ float gelu_f(float x) {
    return 0.5f * x * (1.0f + erff(x * 0.70710678118654752440f));
}

__global__ void fill_kernel(float* __restrict__ out, int n, float val) {
    int i = blockIdx.x * 256 + threadIdx.x;
    if (i < n) out[i] = val;
}

__global__ void k_cvt(const float* __restrict__ in, u16* __restrict__ out, int n) {
    int i = blockIdx.x * 256 + threadIdx.x;
    if (i < n) out[i] = f2b(fs(in[i]));
}

// W (K x N, f32) -> WT (N x Kp, bf16), zero-padded for k >= K
__global__ void k_cvtT(const float* __restrict__ W, u16* __restrict__ WT,
                       int K, int N, int Kp, int total) {
    int id = blockIdx.x * 256 + threadIdx.x;
    if (id >= total) return;
    int n = id / Kp, k = id - n * Kp;
    WT[id] = (k < K) ? f2b(fs(W[(size_t)k * N + n])) : (u16)0;
}

// nbr row (30) + sdiff row (12), one thread per (b,k)
__global__ void k_prep(const float* __restrict__ qobs, const float* __restrict__ qmask,
                       const float* __restrict__ rshift, const int* __restrict__ rsmask,
                       const int* __restrict__ qcode, const int* __restrict__ rcodes,
                       const float* __restrict__ rdist, const float* __restrict__ rc_table,
                       const float* __restrict__ E_res,
                       float* __restrict__ nbr, float* __restrict__ sdiff, int NBc)
{
    int gk = blockIdx.x * 256 + threadIdx.x;
    if (gk >= NBc) return;
    int b = gk >> 5;
    int qc = qcode[b], rc = rcodes[gk];
    int qi = min(max(qc, 0), 20), ri = min(max(rc, 0), 20);
    float dist = fs(rdist[gk]);
    float same = (rc == qc) ? 1.f : 0.f;
    float* nr = nbr + (size_t)gk * 30;
    float* sd = sdiff + (size_t)gk * 12;
    for (int s = 0; s < 6; s++) {
        float rs = fs(rshift[gk * 6 + s]);
        bool m = rsmask[gk * 6 + s] != 0;
        float rq = rc_table[qi * 6 + s];
        float rr = rc_table[ri * 6 + s];
        bool rcv = (rq == rq) && (rr == rr) && fabsf(rq) < 1e30f && fabsf(rr) < 1e30f;
        float sh = (m && rcv) ? (rq + rs - rr) : rs;
        nr[s] = sh;
        nr[6 + s] = m ? 1.f : 0.f;
        float qm = fs(qmask[b * 6 + s]);
        sd[s] = (fs(qobs[b * 6 + s]) - sh) * qm;
        sd[6 + s] = qm;
    }
    for (int j = 0; j < 16; j++) nr[12 + j] = fs(E_res[ri * 16 + j]);
    nr[28] = dist;
    nr[29] = same;
}

// per-(b,s) stats: one wave handles (b, 2 s-values); lanes 0-31 do s0, 32-63 do s0+1
__global__ void k_statsS_w(const float* __restrict__ nbr, const int* __restrict__ rvalid,
                           float* __restrict__ pst, int BCc)
{
    int wid = (blockIdx.x * 256 + threadIdx.x) >> 6;
    int lane = threadIdx.x & 63;
    if (wid >= BCc * 3) return;
    int b = wid / 3, s2 = wid - b * 3;
    int s = s2 * 2 + (lane >> 5), k = lane & 31;
    const float* nr = nbr + (size_t)(b * 32 + k) * 30;
    float vf = (rvalid[b * 32 + k] != 0) ? 1.f : 0.f;
    float vm = vf * nr[6 + s];
    float shv = nr[s], dist = nr[28], same = nr[29];
    float cnt = vm, msum = shv * vm, mdist = dist * vm, mst = same * vm;
#pragma unroll
    for (int m = 1; m <= 16; m <<= 1) {
        cnt += __shfl_xor(cnt, m);
        msum += __shfl_xor(msum, m);
        mdist += __shfl_xor(mdist, m);
        mst += __shfl_xor(mst, m);
    }
    float inv = 1.f / (cnt + 1e-8f);
    float mean = msum * inv;
    float dv = shv - mean;
    float var = dv * dv * vm;
#pragma unroll
    for (int m = 1; m <= 16; m <<= 1) var += __shfl_xor(var, m);
    var *= inv;
    if (k == 0) {
        float* p = pst + (size_t)b * 24 + s * 4;
        p[0] = cnt * (1.f / 32.f);
        p[1] = fminf(fmaxf(log1pf(var), 0.f), 5.f) * 0.2f;
        p[2] = mdist * inv;
        p[3] = mst * inv;
    }
}

// per-b global stats: one wave per b, lanes 0-31 active
__global__ void k_statsG_w(const float* __restrict__ nbr, const int* __restrict__ rvalid,
                           float* __restrict__ gst, float* __restrict__ anyv, int BCc)
{
    int wid = (blockIdx.x * 256 + threadIdx.x) >> 6;
    int lane = threadIdx.x & 63;
    if (wid >= BCc) return;
    int b = wid, k = lane & 31;
    float svf = 0.f, sdm = 0.f, mdm = -1e30f, ssm = 0.f;
    if (lane < 32) {
        const float* nr = nbr + (size_t)(b * 32 + k) * 30;
        float vf = (rvalid[b * 32 + k] != 0) ? 1.f : 0.f;
        float dm = vf * nr[28];
        svf = vf; sdm = dm; mdm = dm; ssm = vf * nr[29];
    }
#pragma unroll
    for (int m = 1; m <= 32; m <<= 1) {
        svf += __shfl_xor(svf, m);
        sdm += __shfl_xor(sdm, m);
        mdm = fmaxf(mdm, __shfl_xor(mdm, m));
        ssm += __shfl_xor(ssm, m);
    }
    if (lane == 0) {
        float* g = gst + (size_t)b * 4;
        g[0] = sdm / (svf + 1e-8f);
        g[1] = mdm;
        g[2] = svf * (1.f / 32.f);
        g[3] = ssm * (1.f / 32.f);
        anyv[b] = (svf > 0.f) ? 1.f : 0.f;
    }
}

// bf16 MFMA GEMM body: C = act(A @ BT^T + bias).
template <int ACT, bool OUTF, bool OUTB>
__device__ __forceinline__ void gemm_body(
    const u16* __restrict__ A, int lda,
    const u16* __restrict__ BT, int ldb,
    const float* __restrict__ bias,
    float* __restrict__ Cf, u16* __restrict__ Cb, int ldc,
    int K, int m0, int n0)
{
    __shared__ u16 As[64 * 72];
    __shared__ u16 Bs[64 * 72];
    const int t = threadIdx.x;
    const int lane = t & 63, wave = t >> 6;
    const int wm = (wave & 1) << 5, wn = (wave >> 1) << 5;
    const int frm = lane & 15, frq = lane >> 4;
    const int r0 = t >> 3, c0 = (t & 7) << 3;
    const f32x4 z = {0.f, 0.f, 0.f, 0.f};
    f32x4 acc[2][2] = {{z, z}, {z, z}};
    for (int k0 = 0; k0 < K; k0 += 64) {
        *(bf16x8*)&As[r0 * 72 + c0]        = *(const bf16x8*)&A[(size_t)(m0 + r0) * lda + k0 + c0];
        *(bf16x8*)&As[(r0 + 32) * 72 + c0] = *(const bf16x8*)&A[(size_t)(m0 + r0 + 32) * lda + k0 + c0];
        *(bf16x8*)&Bs[r0 * 72 + c0]        = *(const bf16x8*)&BT[(size_t)(n0 + r0) * ldb + k0 + c0];
        *(bf16x8*)&Bs[(r0 + 32) * 72 + c0] = *(const bf16x8*)&BT[(size_t)(n0 + r0 + 32) * ldb + k0 + c0];
        __syncthreads();
#pragma unroll
        for (int kk = 0; kk < 2; kk++) {
            const int fo = (kk << 5) + (frq << 3);
            bf16x8 a0 = *(const bf16x8*)&As[(wm + frm) * 72 + fo];
            bf16x8 a1 = *(const bf16x8*)&As[(wm + 16 + frm) * 72 + fo];
            bf16x8 b0 = *(const bf16x8*)&Bs[(wn + frm) * 72 + fo];
            bf16x8 b1 = *(const bf16x8*)&Bs[(wn + 16 + frm) * 72 + fo];
            acc[0][0] = __builtin_amdgcn_mfma_f32_16x16x32_bf16(a0, b0, acc[0][0], 0, 0, 0);
            acc[0][1] = __builtin_amdgcn_mfma_f32_16x16x32_bf16(a0, b1, acc[0][1], 0, 0, 0);
            acc[1][0] = __builtin_amdgcn_mfma_f32_16x16x32_bf16(a1, b0, acc[1][0], 0, 0, 0);
            acc[1][1] = __builtin_amdgcn_mfma_f32_16x16x32_bf16(a1, b1, acc[1][1], 0, 0, 0);
        }
        __syncthreads();
    }
#pragma unroll
    for (int mi = 0; mi < 2; mi++) {
#pragma unroll
        for (int ni = 0; ni < 2; ni++) {
            int col = n0 + wn + (ni << 4) + frm;
            float bv = bias ? fs(bias[col]) : 0.f;
#pragma unroll
            for (int r = 0; r < 4; r++) {
                int row = m0 + wm + (mi << 4) + (frq << 2) + r;
                float v = acc[mi][ni][r] + bv;
                if (ACT == 1) v = gelu_f(v);
                if (OUTF) Cf[(size_t)row * ldc + col] = v;
                if (OUTB) Cb[(size_t)row * ldc + col] = f2b(v);
            }
        }
    }
}

template <int ACT, bool OUTF, bool OUTB>
__global__ __launch_bounds__(256) void k_gemm_bb(
    const u16* __restrict__ A, int lda, const u16* __restrict__ BT, int ldb,
    const float* __restrict__ bias, float* __restrict__ Cf, u16* __restrict__ Cb,
    int ldc, int K)
{
    gemm_body<ACT, OUTF, OUTB>(A, lda, BT, ldb, bias, Cf, Cb, ldc, K,
                               blockIdx.y << 6, blockIdx.x << 6);
}

// Qp[b, hd*384+j] = sum_d Qh[b, hd*64+d] * Wak[j, hd*64+d]   (bf16 out)
__global__ __launch_bounds__(256) void k_qp_bb(
    const u16* __restrict__ Qhb, const u16* __restrict__ WakB, u16* __restrict__ Qpb)
{
    int hd = blockIdx.z;
    gemm_body<0, false, true>(Qhb + hd * 64, 384, WakB + hd * 64, 384, nullptr,
                              nullptr, Qpb + hd * 384, 2304, 64,
                              blockIdx.y << 6, blockIdx.x << 6);
}

// attn[b, hd*64+n] = sum_j vms[b, hd*384+j] * Wav[j, hd*64+n] + bav[hd*64+n]
__global__ __launch_bounds__(256) void k_attnout_bb(
    const u16* __restrict__ vmsb, const u16* __restrict__ WavT,
    const float* __restrict__ bav, u16* __restrict__ attnb)
{
    int hd = blockIdx.x;
    gemm_body<0, false, true>(vmsb + hd * 384, 2304, WavT + (size_t)hd * 64 * 384, 384,
                              bav + hd * 64, nullptr, attnb + hd * 64, 384, 384,
                              blockIdx.y << 6, 0);
}

// fused score-bias MLP: one block per b (192 threads); hid + Wss2 in LDS
__global__ __launch_bounds__(192) void k_mlpbias(
    const float* __restrict__ sdiff, const float* __restrict__ Wss1,
    const float* __restrict__ bss1, const float* __restrict__ Wss2,
    const float* __restrict__ bss2, float* __restrict__ bias_s)
{
    __shared__ float sdS[32 * 12];
    __shared__ float hidS[32 * 193];
    __shared__ float w2S[1152];
    const int b = blockIdx.x;
    const int t = threadIdx.x;
    for (int i = t; i < 384; i += 192) sdS[i] = sdiff[(size_t)b * 384 + i];
    for (int i = t; i < 1152; i += 192) w2S[i] = fs(Wss2[i]);
    __syncthreads();
    {
        float w[12];
#pragma unroll
        for (int j = 0; j < 12; j++) w[j] = fs(Wss1[j * 192 + t]);
        float b1 = fs(bss1[t]);
        for (int k = 0; k < 32; k++) {
            float acc = b1;
#pragma unroll
            for (int j = 0; j < 12; j++) acc += sdS[k * 12 + j] * w[j];
            hidS[k * 193 + t] = gelu_f(acc);
        }
    }
    __syncthreads();
    {
        int k = t / 6, s = t - k * 6;
        float acc = fs(bss2[s]);
        for (int n = 0; n < 192; n++) acc += hidS[k * 193 + n] * w2S[n * 6 + s];
        bias_s[(size_t)(b * 32 + k) * 6 + s] = acc;
    }
}

// qkb[b,h]: one wave per (b,h)
__global__ void k_qkb_w(const float* __restrict__ Qh, const float* __restrict__ bak,
                        float* __restrict__ qkb, int BCc)
{
    int wid = (blockIdx.x * 256 + threadIdx.x) >> 6;
    int lane = threadIdx.x & 63;
    if (wid >= BCc * 6) return;
    int b = wid / 6, h = wid - b * 6;
    float acc = Qh[(size_t)b * 384 + h * 64 + lane] * fs(bak[h * 64 + lane]);
#pragma unroll
    for (int m = 1; m <= 32; m <<= 1) acc += __shfl_xor(acc, m);
    if (lane == 0) qkb[b * 6 + h] = acc;
}

// attention core: bf16 kv in LDS (u16 stride 386 = 193 words, conflict-free),
// bf16 q, wave-parallel softmax, vms out bf16 to its own buffer.
__global__ __launch_bounds__(384) void k_attnblk(
    const float* __restrict__ nbr, const float* __restrict__ Wnp,
    const float* __restrict__ bnp, const u16* __restrict__ Qpb,
    const float* __restrict__ qkb, const float* __restrict__ bias_s,
    const int* __restrict__ rvalid, const float* __restrict__ anyv,
    u16* __restrict__ vmsb)
{
    __shared__ u16 kvsb[32 * 386];
    __shared__ u16 qSb[2304];
    __shared__ float wsx[192];
    const int b = blockIdx.x;
    const int t = threadIdx.x;
    for (int i = t; i < 1152; i += 384)
        ((u32*)qSb)[i] = ((const u32*)(Qpb + (size_t)b * 2304))[i];
    {   // stage A: kv = gelu(nbr row . Wnp col + bnp) -> bf16
        float w[30];
#pragma unroll
        for (int j = 0; j < 30; j++) w[j] = fs(Wnp[j * 384 + t]);
        float bb = fs(bnp[t]);
        const float* nr = nbr + (size_t)b * 960;
        for (int k = 0; k < 32; k++) {
            float acc = bb;
#pragma unroll
            for (int j = 0; j < 30; j++) acc += nr[k * 30 + j] * w[j];
            kvsb[k * 386 + t] = f2b(gelu_f(acc));
        }
    }
    __syncthreads();
    {   // stage B: scores + wave-parallel softmax (wave = head, lane pairs split dot)
        const int p = t >> 1, half = t & 1;
        const int h = p >> 5, k = p & 31;
        const u32* kr = (const u32*)&kvsb[k * 386 + half * 192];
        const u32* qr = (const u32*)&qSb[h * 384 + half * 192];
        float acc = 0.f;
#pragma unroll 8
        for (int j2 = 0; j2 < 96; j2++) {
            u32 kw = kr[j2], qw = qr[j2];
            union { u32 u; float f; } a0, a1, c0, c1;
            a0.u = kw << 16; a1.u = kw & 0xffff0000u;
            c0.u = qw << 16; c1.u = qw & 0xffff0000u;
            acc += a0.f * c0.f;
            acc += a1.f * c1.f;
        }
        acc += __shfl_xor(acc, 1);
        float s = (acc + qkb[b * 6 + h]) * 0.125f + bias_s[(size_t)(b * 32 + k) * 6 + h];
        bool ve = (rvalid[b * 32 + k] != 0) || (anyv[b] == 0.f && k == 0);
        s = ve ? s : -10000.f;
        float mx = s;
        mx = fmaxf(mx, __shfl_xor(mx, 2));
        mx = fmaxf(mx, __shfl_xor(mx, 4));
        mx = fmaxf(mx, __shfl_xor(mx, 8));
        mx = fmaxf(mx, __shfl_xor(mx, 16));
        mx = fmaxf(mx, __shfl_xor(mx, 32));
        float e = expf(s - mx);
        float sum = e;
        sum += __shfl_xor(sum, 2);
        sum += __shfl_xor(sum, 4);
        sum += __shfl_xor(sum, 8);
        sum += __shfl_xor(sum, 16);
        sum += __shfl_xor(sum, 32);
        if (half == 0) wsx[h * 32 + k] = e / sum;
    }
    __syncthreads();
    {   // stage C: vms[h][t] = sum_k w[h][k]*kv[k][t] -> bf16
        float a0 = 0.f, a1 = 0.f, a2 = 0.f, a3 = 0.f, a4 = 0.f, a5 = 0.f;
        for (int k = 0; k < 32; k++) {
            float kvv = b2f(kvsb[k * 386 + t]);
            a0 += wsx[k] * kvv;
            a1 += wsx[32 + k] * kvv;
            a2 += wsx[64 + k] * kvv;
            a3 += wsx[96 + k] * kvv;
            a4 += wsx[128 + k] * kvv;
            a5 += wsx[160 + k] * kvv;
        }
        u16* vp = vmsb + (size_t)b * 2304;
        vp[t] = f2b(a0);
        vp[384 + t] = f2b(a1);
        vp[768 + t] = f2b(a2);
        vp[1152 + t] = f2b(a3);
        vp[1536 + t] = f2b(a4);
        vp[1920 + t] = f2b(a5);
    }
}

__global__ void k_ctxout(const float* __restrict__ ctx, const float* __restrict__ anyv,
                         const float* __restrict__ fctx, float* __restrict__ out, int BCc)
{
    int id = blockIdx.x * 256 + threadIdx.x;
    if (id >= BCc * 384) return;
    int b = id / 384, c = id - b * 384;
    float v = (anyv[b] > 0.f) ? ctx[id] : fs(fctx[c]);
    out[id] = fin(v);
}

// assemble trust-input X as bf16, row stride 448 (zero pad 420..447)
__global__ void k_xtc_b(const float* __restrict__ tqf, const int* __restrict__ qcode,
                        const float* __restrict__ Etr, const float* __restrict__ gst,
                        u16* __restrict__ Xb, int BCc)
{
    int id = blockIdx.x * 256 + threadIdx.x;
    if (id >= BCc * 448) return;
    int b = id / 448, c = id - b * 448;
    float v;
    if (c < 384) v = tqf[(size_t)b * 384 + c];
    else if (c < 416) v = fs(Etr[min(max(qcode[b], 0), 20) * 32 + (c - 384)]);
    else if (c < 420) v = gst[(size_t)b * 4 + (c - 416)];
    else v = 0.f;
    Xb[id] = f2b(v);
}

// swb[b,s]: one wave per (b,s)
__global__ void k_swb_w(const float* __restrict__ s1f, const float* __restrict__ Wsw2,
                        const float* __restrict__ bsw2, float* __restrict__ swb, int BCc)
{
    int wid = (blockIdx.x * 256 + threadIdx.x) >> 6;
    int lane = threadIdx.x & 63;
    if (wid >= BCc * 6) return;
    int b = wid / 6, s = wid - b * 6;
    float acc = 0.f;
#pragma unroll
    for (int i = 0; i < 6; i++) {
        int n = lane + 64 * i;
        acc += s1f[(size_t)b * 384 + n] * fs(Wsw2[n * 6 + s]);
    }
#pragma unroll
    for (int m = 1; m <= 32; m <<= 1) acc += __shfl_xor(acc, m);
    if (lane == 0) swb[b * 6 + s] = acc + fs(bsw2[s]);
}

// transfer: one wave per (b, s-pair); lanes split as (s_half, k)
__global__ void k_transfer_w(const float* __restrict__ nbr, const int* __restrict__ rsmask,
                             const int* __restrict__ rvalid, const float* __restrict__ swb,
                             const float* __restrict__ anyv, const float* __restrict__ sscale,
                             const float* __restrict__ fshift, float* __restrict__ out, int BCc)
{
    int wid = (blockIdx.x * 256 + threadIdx.x) >> 6;
    int lane = threadIdx.x & 63;
    if (wid >= BCc * 3) return;
    int b = wid / 3, s2 = wid - b * 3;
    int s = s2 * 2 + (lane >> 5), k = lane & 31;
    if (anyv[b] <= 0.f) {
        if (k == 0) out[b * 6 + s] = fin(fs(fshift[s]));
        return;
    }
    int gk = b * 32 + k;
    const float* nr = nbr + (size_t)gk * 30;
    float wb = swb[b * 6 + s] * 0.1f;
    bool m = (rvalid[gk] != 0) && (rsmask[gk * 6 + s] != 0);
    float wv = m ? (nr[28] + nr[29] * 0.5f + wb) : -10000.f;
    float mx = wv;
#pragma unroll
    for (int mm = 1; mm <= 16; mm <<= 1) mx = fmaxf(mx, __shfl_xor(mx, mm));
    float e = expf(wv - mx);
    float num = e * nr[s], den = e;
#pragma unroll
    for (int mm = 1; mm <= 16; mm <<= 1) {
        num += __shfl_xor(num, mm);
        den += __shfl_xor(den, mm);
    }
    if (k == 0) out[b * 6 + s] = fin((num / den) * fs(sscale[s]));
}

// trust: one wave per (b,s); each lane covers 3 hidden units
__global__ void k_trust_w(const float* __restrict__ tcp, const float* __restrict__ pst,
                          const float* __restrict__ Wtp1, const float* __restrict__ Wtp2,
                          const float* __restrict__ btp2, float* __restrict__ out, int BCc)
{
    int wid = (blockIdx.x * 256 + threadIdx.x) >> 6;
    int lane = threadIdx.x & 63;
    if (wid >= BCc * 6) return;
    int b = wid / 6, s = wid - b * 6;
    const float* ps = pst + (size_t)b * 24 + s * 4;
    float p0 = ps[0], p1 = ps[1], p2 = ps[2], p3 = ps[3];
    float acc = 0.f;
#pragma unroll
    for (int i = 0; i < 3; i++) {
        int j = lane + 64 * i;
        float pre = tcp[(size_t)b * 192 + j];
        pre += p0 * fs(Wtp1[(size_t)384 * 192 + j]);
        pre += p1 * fs(Wtp1[(size_t)385 * 192 + j]);
        pre += p2 * fs(Wtp1[(size_t)386 * 192 + j]);
        pre += p3 * fs(Wtp1[(size_t)387 * 192 + j]);
        acc += gelu_f(pre) * fs(Wtp2[j]);
    }
#pragma unroll
    for (int m = 1; m <= 32; m <<= 1) acc += __shfl_xor(acc, m);
    if (lane == 0) {
        float tv = 1.f / (1.f + expf(-(acc + fs(btp2[0]))));
        out[b * 6 + s] = fin(tv);
    }
}

#define L1(total) <<<((total) + 255) / 256, 256, 0, stream>>>
#define LW(nwaves) <<<(((nwaves) * 64) + 255) / 256, 256, 0, stream>>>

extern "C" void kernel_launch(void* const* d_in, const int* in_sizes, int n_in,
                              void* d_out, int out_size, void* d_ws, size_t ws_size,
                              hipStream_t stream)
{
    float* out = (float*)d_out;

    static const int EXP[45] = {
        2097152, 4096, 24576, 24576, 786432, 786432, 131072, 131072, 131072, 126,
        196608, 384, 336, 11520, 384, 147456, 384, 147456, 384, 147456, 384,
        2304, 192, 1152, 6, 147456, 384, 147456, 384, 147456, 384, 2304, 6,
        672, 196608, 384, 161280, 384, 74496, 192, 192, 1, 6, 6, 384
    };
    if (n_in != 45) {
        fill_kernel L1(out_size)(out, out_size, 580.0f);
        return;
    }
    for (int i = 0; i < 45; i++) {
        if (in_sizes[i] != EXP[i]) {
            fill_kernel L1(out_size)(out, out_size, 600.0f + 4.0f * i);
            return;
        }
    }

    const float* i_qe    = (const float*)d_in[0];
    const int*   i_qcode = (const int*)d_in[1];
    const float* i_qobs  = (const float*)d_in[2];
    const float* i_qmask = (const float*)d_in[3];
    const float* i_rshift= (const float*)d_in[4];
    const int*   i_rsmask= (const int*)d_in[5];
    const int*   i_rcodes= (const int*)d_in[6];
    const float* i_rdist = (const float*)d_in[7];
    const int*   i_rvalid= (const int*)d_in[8];
    const float* i_rc    = (const float*)d_in[9];
    const float* i_Wqp   = (const float*)d_in[10];
    const float* i_bqp   = (const float*)d_in[11];
    const float* i_Eres  = (const float*)d_in[12];
    const float* i_Wnp   = (const float*)d_in[13];
    const float* i_bnp   = (const float*)d_in[14];
    const float* i_Waq   = (const float*)d_in[15];
    const float* i_baq   = (const float*)d_in[16];
    const float* i_Wak   = (const float*)d_in[17];
    const float* i_bak   = (const float*)d_in[18];
    const float* i_Wav   = (const float*)d_in[19];
    const float* i_bav   = (const float*)d_in[20];
    const float* i_Wss1  = (const float*)d_in[21];
    const float* i_bss1  = (const float*)d_in[22];
    const float* i_Wss2  = (const float*)d_in[23];
    const float* i_bss2  = (const float*)d_in[24];
    const float* i_Wcp1  = (const float*)d_in[25];
    const float* i_bcp1  = (const float*)d_in[26];
    const float* i_Wcp2  = (const float*)d_in[27];
    const float* i_bcp2  = (const float*)d_in[28];
    const float* i_Wsw1  = (const float*)d_in[29];
    const float* i_bsw1  = (const float*)d_in[30];
    const float* i_Wsw2  = (const float*)d_in[31];
    const float* i_bsw2  = (const float*)d_in[32];
    const float* i_Etr   = (const float*)d_in[33];
    const float* i_Wtq   = (const float*)d_in[34];
    const float* i_btq   = (const float*)d_in[35];
    const float* i_Wtc   = (const float*)d_in[36];
    const float* i_btc   = (const float*)d_in[37];
    const float* i_Wtp1  = (const float*)d_in[38];
    const float* i_btp1  = (const float*)d_in[39];
    const float* i_Wtp2  = (const float*)d_in[40];
    const float* i_btp2  = (const float*)d_in[41];
    const float* i_sscale= (const float*)d_in[42];
    const float* i_fshift= (const float*)d_in[43];
    const float* i_fctx  = (const float*)d_in[44];

    auto layoutBytes = [](int bc) -> size_t {
        auto al = [](size_t x) { return (x + 255) & ~(size_t)255; };
        size_t off = 0;
        off += al(2097152ull * 2);
        off += al(196608ull * 2) * 2;
        off += al(147456ull * 2) * 6;
        off += al(172032ull * 2);
        off += al(73728ull * 2);
        size_t nb = (size_t)bc * 32;
        off += al(nb * 30 * 4) + al(nb * 12 * 4) + al(nb * 6 * 4);
        off += al((size_t)bc * 384 * 4) * 4;
        off += al((size_t)bc * 192 * 4);
        off += al((size_t)bc * 2304 * 2) * 2;
        off += al((size_t)bc * 384 * 2) * 5;
        off += al((size_t)bc * 448 * 2);
        off += al((size_t)bc * 6 * 4) * 2 + al((size_t)bc * 24 * 4)
             + al((size_t)bc * 4 * 4) + al((size_t)bc * 4);
        return off;
    };
    const int cand[7] = {4096, 2048, 1024, 512, 256, 128, 64};
    int BCc = 64;
    for (int i = 0; i < 7; i++) {
        if (layoutBytes(cand[i]) <= ws_size) { BCc = cand[i]; break; }
    }
    const int NBc = BCc * 32;

    char* wsb = (char*)d_ws;
    size_t off = 0;
    auto allocB = [&](size_t bytes) -> void* {
        void* p = (void*)(wsb + off);
        off = (off + bytes + 255) & ~(size_t)255;
        return p;
    };
    u16* qeb    = (u16*)allocB(2097152ull * 2);
    u16* WqpT   = (u16*)allocB(196608ull * 2);
    u16* WtqT   = (u16*)allocB(196608ull * 2);
    u16* WaqT   = (u16*)allocB(147456ull * 2);
    u16* WakB   = (u16*)allocB(147456ull * 2);
    u16* WavT   = (u16*)allocB(147456ull * 2);
    u16* Wcp1T  = (u16*)allocB(147456ull * 2);
    u16* Wcp2T  = (u16*)allocB(147456ull * 2);
    u16* Wsw1T  = (u16*)allocB(147456ull * 2);
    u16* WtcT   = (u16*)allocB(172032ull * 2);
    u16* Wtp1T  = (u16*)allocB(73728ull * 2);
    float* nbr   = (float*)allocB((size_t)NBc * 30 * 4);
    float* sdiff = (float*)allocB((size_t)NBc * 12 * 4);
    float* bias_s= (float*)allocB((size_t)NBc * 6 * 4);
    float* tqf   = (float*)allocB((size_t)BCc * 384 * 4);
    float* Qhf   = (float*)allocB((size_t)BCc * 384 * 4);
    float* s1f   = (float*)allocB((size_t)BCc * 384 * 4);
    float* ctxf  = (float*)allocB((size_t)BCc * 384 * 4);
    float* tcpf  = (float*)allocB((size_t)BCc * 192 * 4);
    u16*   Qpb   = (u16*)allocB((size_t)BCc * 2304 * 2);
    u16*   vmsb  = (u16*)allocB((size_t)BCc * 2304 * 2);
    u16*   qfb   = (u16*)allocB((size_t)BCc * 384 * 2);
    u16*   Qhb   = (u16*)allocB((size_t)BCc * 384 * 2);
    u16*   attnb = (u16*)allocB((size_t)BCc * 384 * 2);
    u16*   h1b   = (u16*)allocB((size_t)BCc * 384 * 2);
    u16*   tcb   = (u16*)allocB((size_t)BCc * 384 * 2);
    u16*   Xfb   = (u16*)allocB((size_t)BCc * 448 * 2);
    float* swbf  = (float*)allocB((size_t)BCc * 6 * 4);
    float* qkbf  = (float*)allocB((size_t)BCc * 6 * 4);
    float* pstf  = (float*)allocB((size_t)BCc * 24 * 4);
    float* gstf  = (float*)allocB((size_t)BCc * 4 * 4);
    float* anyf  = (float*)allocB((size_t)BCc * 4);

    if (off > ws_size) {
        fill_kernel L1(out_size)(out, out_size, 1000.0f);
        return;
    }

    k_cvt L1(2097152)(i_qe, qeb, 2097152);
    k_cvtT L1(196608)(i_Wqp, WqpT, 512, 384, 512, 196608);
    k_cvtT L1(196608)(i_Wtq, WtqT, 512, 384, 512, 196608);
    k_cvtT L1(147456)(i_Waq, WaqT, 384, 384, 384, 147456);
    k_cvt L1(147456)(i_Wak, WakB, 147456);
    k_cvtT L1(147456)(i_Wav, WavT, 384, 384, 384, 147456);
    k_cvtT L1(147456)(i_Wcp1, Wcp1T, 384, 384, 384, 147456);
    k_cvtT L1(147456)(i_Wcp2, Wcp2T, 384, 384, 384, 147456);
    k_cvtT L1(147456)(i_Wsw1, Wsw1T, 384, 384, 384, 147456);
    k_cvtT L1(172032)(i_Wtc, WtcT, 420, 384, 448, 172032);
    k_cvtT L1(73728)(i_Wtp1, Wtp1T, 384, 192, 384, 73728);

    for (int c = 0; c < 4096 / BCc; c++) {
        const size_t B0 = (size_t)c * BCc;
        const dim3 g6(6, BCc / 64), g3(3, BCc / 64);
        const dim3 gqp(6, BCc / 64, 6), gao(6, BCc / 64);
        k_prep L1(NBc)(i_qobs + B0 * 6, i_qmask + B0 * 6, i_rshift + B0 * 192,
                       i_rsmask + B0 * 192, i_qcode + B0, i_rcodes + B0 * 32,
                       i_rdist + B0 * 32, i_rc, i_Eres, nbr, sdiff, NBc);
        k_statsS_w LW(BCc * 3)(nbr, i_rvalid + B0 * 32, pstf, BCc);
        k_statsG_w LW(BCc)(nbr, i_rvalid + B0 * 32, gstf, anyf, BCc);
        k_mlpbias<<<BCc, 192, 0, stream>>>(sdiff, i_Wss1, i_bss1, i_Wss2, i_bss2, bias_s);
        k_gemm_bb<1, false, true><<<g6, 256, 0, stream>>>(
            qeb + B0 * 512, 512, WqpT, 512, i_bqp, nullptr, qfb, 384, 512);
        k_gemm_bb<1, true, false><<<g6, 256, 0, stream>>>(
            qeb + B0 * 512, 512, WtqT, 512, i_btq, tqf, nullptr, 384, 512);
        k_gemm_bb<0, true, true><<<g6, 256, 0, stream>>>(
            qfb, 384, WaqT, 384, i_baq, Qhf, Qhb, 384, 384);
        k_qp_bb<<<gqp, 256, 0, stream>>>(Qhb, WakB, Qpb);
        k_qkb_w LW(BCc * 6)(Qhf, i_bak, qkbf, BCc);
        k_attnblk<<<BCc, 384, 0, stream>>>(nbr, i_Wnp, i_bnp, Qpb, qkbf, bias_s,
                                           i_rvalid + B0 * 32, anyf, vmsb);
        k_attnout_bb<<<gao, 256, 0, stream>>>(vmsb, WavT, i_bav, attnb);
        k_gemm_bb<1, false, true><<<g6, 256, 0, stream>>>(
            attnb, 384, Wcp1T, 384, i_bcp1, nullptr, h1b, 384, 384);
        k_gemm_bb<0, true, false><<<g6, 256, 0, stream>>>(
            h1b, 384, Wcp2T, 384, i_bcp2, ctxf, nullptr, 384, 384);
        k_gemm_bb<1, true, false><<<g6, 256, 0, stream>>>(
            attnb, 384, Wsw1T, 384, i_bsw1, s1f, nullptr, 384, 384);
        k_swb_w LW(BCc * 6)(s1f, i_Wsw2, i_bsw2, swbf, BCc);
        k_ctxout L1(BCc * 384)(ctxf, anyf, i_fctx, out + B0 * 384, BCc);
        k_xtc_b L1(BCc * 448)(tqf, i_qcode + B0, i_Etr, gstf, Xfb, BCc);
        k_gemm_bb<1, false, true><<<g6, 256, 0, stream>>>(
            Xfb, 448, WtcT, 448, i_btc, nullptr, tcb, 384, 448);
        k_gemm_bb<0, true, false><<<g3, 256, 0, stream>>>(
            tcb, 384, Wtp1T, 384, i_btp1, tcpf, nullptr, 192, 384);
        k_trust_w LW(BCc * 6)(tcpf, pstf, i_Wtp1, i_Wtp2, i_btp2,
                              out + (size_t)4096 * 390 + B0 * 6, BCc);
        k_transfer_w LW(BCc * 3)(nbr, i_rsmask + B0 * 192, i_rvalid + B0 * 32, swbf, anyf,
                                 i_sscale, i_fshift, out + (size_t)4096 * 384 + B0 * 6, BCc);
    }
}

// Round 7
// 441.984 us; speedup vs baseline: 3.9746x; 1.2592x over previous
//
#include <hip/hip_runtime.h>

typedef unsigned short u16;
typedef unsigned int u32;
typedef __attribute__((ext_vector_type(8))) short bf16x8;
typedef __attribute__((ext_vector_type(4))) float f32x4;

__device__ __forceinline__ float fs(float f) {
    return (f == f && fabsf(f) < 1e30f) ? f : 0.f;
}
__device__ __forceinline__ float fin(float v) {
    return (v == v && fabsf(v) < 1e30f) ? v : 555.0f;
}
__device__ __forceinline__ u16 f2b(float f) {
    union { float f; unsigned int i; } w; w.f = f;
    unsigned int r = w.i + 0x7FFFu + ((w.i >> 16) & 1u);
    return (u16)(r >> 16);
}
__device__ __forceinline__ float b2f(u16 b) {
    union { unsigned int i; float f; } w; w.i = ((unsigned int)b) << 16;
    return w.f;
}
__device__ __forceinline__ float gelu_f(float x) {
    return 0.5f * x * (1.0f + erff(x * 0.70710678118654752440f));
}

__global__ void fill_kernel(float* __restrict__ out, int n, float val) {
    int i = blockIdx.x * 256 + threadIdx.x;
    if (i < n) out[i] = val;
}

__global__ void k_cvt(const float* __restrict__ in, u16* __restrict__ out, int n) {
    int i = blockIdx.x * 256 + threadIdx.x;
    if (i < n) out[i] = f2b(fs(in[i]));
}

// W (K x N, f32) -> WT (N x Kp, bf16), zero-padded for k >= K
__global__ void k_cvtT(const float* __restrict__ W, u16* __restrict__ WT,
                       int K, int N, int Kp, int total) {
    int id = blockIdx.x * 256 + threadIdx.x;
    if (id >= total) return;
    int n = id / Kp, k = id - n * Kp;
    WT[id] = (k < K) ? f2b(fs(W[(size_t)k * N + n])) : (u16)0;
}

// nbr row (30) + sdiff row (12), one thread per (b,k)
__global__ void k_prep(const float* __restrict__ qobs, const float* __restrict__ qmask,
                       const float* __restrict__ rshift, const int* __restrict__ rsmask,
                       const int* __restrict__ qcode, const int* __restrict__ rcodes,
                       const float* __restrict__ rdist, const float* __restrict__ rc_table,
                       const float* __restrict__ E_res,
                       float* __restrict__ nbr, float* __restrict__ sdiff, int NBc)
{
    int gk = blockIdx.x * 256 + threadIdx.x;
    if (gk >= NBc) return;
    int b = gk >> 5;
    int qc = qcode[b], rc = rcodes[gk];
    int qi = min(max(qc, 0), 20), ri = min(max(rc, 0), 20);
    float dist = fs(rdist[gk]);
    float same = (rc == qc) ? 1.f : 0.f;
    float* nr = nbr + (size_t)gk * 30;
    float* sd = sdiff + (size_t)gk * 12;
    for (int s = 0; s < 6; s++) {
        float rs = fs(rshift[gk * 6 + s]);
        bool m = rsmask[gk * 6 + s] != 0;
        float rq = rc_table[qi * 6 + s];
        float rr = rc_table[ri * 6 + s];
        bool rcv = (rq == rq) && (rr == rr) && fabsf(rq) < 1e30f && fabsf(rr) < 1e30f;
        float sh = (m && rcv) ? (rq + rs - rr) : rs;
        nr[s] = sh;
        nr[6 + s] = m ? 1.f : 0.f;
        float qm = fs(qmask[b * 6 + s]);
        sd[s] = (fs(qobs[b * 6 + s]) - sh) * qm;
        sd[6 + s] = qm;
    }
    for (int j = 0; j < 16; j++) nr[12 + j] = fs(E_res[ri * 16 + j]);
    nr[28] = dist;
    nr[29] = same;
}

// per-(b,s) stats: one wave handles (b, 2 s-values)
__global__ void k_statsS_w(const float* __restrict__ nbr, const int* __restrict__ rvalid,
                           float* __restrict__ pst, int BCc)
{
    int wid = (blockIdx.x * 256 + threadIdx.x) >> 6;
    int lane = threadIdx.x & 63;
    if (wid >= BCc * 3) return;
    int b = wid / 3, s2 = wid - b * 3;
    int s = s2 * 2 + (lane >> 5), k = lane & 31;
    const float* nr = nbr + (size_t)(b * 32 + k) * 30;
    float vf = (rvalid[b * 32 + k] != 0) ? 1.f : 0.f;
    float vm = vf * nr[6 + s];
    float shv = nr[s], dist = nr[28], same = nr[29];
    float cnt = vm, msum = shv * vm, mdist = dist * vm, mst = same * vm;
#pragma unroll
    for (int m = 1; m <= 16; m <<= 1) {
        cnt += __shfl_xor(cnt, m);
        msum += __shfl_xor(msum, m);
        mdist += __shfl_xor(mdist, m);
        mst += __shfl_xor(mst, m);
    }
    float inv = 1.f / (cnt + 1e-8f);
    float mean = msum * inv;
    float dv = shv - mean;
    float var = dv * dv * vm;
#pragma unroll
    for (int m = 1; m <= 16; m <<= 1) var += __shfl_xor(var, m);
    var *= inv;
    if (k == 0) {
        float* p = pst + (size_t)b * 24 + s * 4;
        p[0] = cnt * (1.f / 32.f);
        p[1] = fminf(fmaxf(log1pf(var), 0.f), 5.f) * 0.2f;
        p[2] = mdist * inv;
        p[3] = mst * inv;
    }
}

// per-b global stats: one wave per b
__global__ void k_statsG_w(const float* __restrict__ nbr, const int* __restrict__ rvalid,
                           float* __restrict__ gst, float* __restrict__ anyv, int BCc)
{
    int wid = (blockIdx.x * 256 + threadIdx.x) >> 6;
    int lane = threadIdx.x & 63;
    if (wid >= BCc) return;
    int b = wid, k = lane & 31;
    float svf = 0.f, sdm = 0.f, mdm = -1e30f, ssm = 0.f;
    if (lane < 32) {
        const float* nr = nbr + (size_t)(b * 32 + k) * 30;
        float vf = (rvalid[b * 32 + k] != 0) ? 1.f : 0.f;
        float dm = vf * nr[28];
        svf = vf; sdm = dm; mdm = dm; ssm = vf * nr[29];
    }
#pragma unroll
    for (int m = 1; m <= 32; m <<= 1) {
        svf += __shfl_xor(svf, m);
        sdm += __shfl_xor(sdm, m);
        mdm = fmaxf(mdm, __shfl_xor(mdm, m));
        ssm += __shfl_xor(ssm, m);
    }
    if (lane == 0) {
        float* g = gst + (size_t)b * 4;
        g[0] = sdm / (svf + 1e-8f);
        g[1] = mdm;
        g[2] = svf * (1.f / 32.f);
        g[3] = ssm * (1.f / 32.f);
        anyv[b] = (svf > 0.f) ? 1.f : 0.f;
    }
}

// bf16 MFMA GEMM body: C = act(A @ BT^T + bias). bias1 (optional) used for col>=384.
template <int ACT, bool OUTF, bool OUTB>
__device__ __forceinline__ void gemm_body(
    const u16* __restrict__ A, int lda,
    const u16* __restrict__ BT, int ldb,
    const float* __restrict__ bias, const float* __restrict__ bias1,
    float* __restrict__ Cf, u16* __restrict__ Cb, int ldc,
    int K, int m0, int n0)
{
    __shared__ u16 As[64 * 72];
    __shared__ u16 Bs[64 * 72];
    const int t = threadIdx.x;
    const int lane = t & 63, wave = t >> 6;
    const int wm = (wave & 1) << 5, wn = (wave >> 1) << 5;
    const int frm = lane & 15, frq = lane >> 4;
    const int r0 = t >> 3, c0 = (t & 7) << 3;
    const f32x4 z = {0.f, 0.f, 0.f, 0.f};
    f32x4 acc[2][2] = {{z, z}, {z, z}};
    for (int k0 = 0; k0 < K; k0 += 64) {
        *(bf16x8*)&As[r0 * 72 + c0]        = *(const bf16x8*)&A[(size_t)(m0 + r0) * lda + k0 + c0];
        *(bf16x8*)&As[(r0 + 32) * 72 + c0] = *(const bf16x8*)&A[(size_t)(m0 + r0 + 32) * lda + k0 + c0];
        *(bf16x8*)&Bs[r0 * 72 + c0]        = *(const bf16x8*)&BT[(size_t)(n0 + r0) * ldb + k0 + c0];
        *(bf16x8*)&Bs[(r0 + 32) * 72 + c0] = *(const bf16x8*)&BT[(size_t)(n0 + r0 + 32) * ldb + k0 + c0];
        __syncthreads();
#pragma unroll
        for (int kk = 0; kk < 2; kk++) {
            const int fo = (kk << 5) + (frq << 3);
            bf16x8 a0 = *(const bf16x8*)&As[(wm + frm) * 72 + fo];
            bf16x8 a1 = *(const bf16x8*)&As[(wm + 16 + frm) * 72 + fo];
            bf16x8 b0 = *(const bf16x8*)&Bs[(wn + frm) * 72 + fo];
            bf16x8 b1 = *(const bf16x8*)&Bs[(wn + 16 + frm) * 72 + fo];
            acc[0][0] = __builtin_amdgcn_mfma_f32_16x16x32_bf16(a0, b0, acc[0][0], 0, 0, 0);
            acc[0][1] = __builtin_amdgcn_mfma_f32_16x16x32_bf16(a0, b1, acc[0][1], 0, 0, 0);
            acc[1][0] = __builtin_amdgcn_mfma_f32_16x16x32_bf16(a1, b0, acc[1][0], 0, 0, 0);
            acc[1][1] = __builtin_amdgcn_mfma_f32_16x16x32_bf16(a1, b1, acc[1][1], 0, 0, 0);
        }
        __syncthreads();
    }
#pragma unroll
    for (int mi = 0; mi < 2; mi++) {
#pragma unroll
        for (int ni = 0; ni < 2; ni++) {
            int col = n0 + wn + (ni << 4) + frm;
            float bv = 0.f;
            if (bias) {
                if (bias1 && col >= 384) bv = fs(bias1[col - 384]);
                else bv = fs(bias[col]);
            }
#pragma unroll
            for (int r = 0; r < 4; r++) {
                int row = m0 + wm + (mi << 4) + (frq << 2) + r;
                float v = acc[mi][ni][r] + bv;
                if (ACT == 1) v = gelu_f(v);
                if (OUTF) Cf[(size_t)row * ldc + col] = v;
                if (OUTB) Cb[(size_t)row * ldc + col] = f2b(v);
            }
        }
    }
}

template <int ACT, bool OUTF, bool OUTB>
__global__ __launch_bounds__(256) void k_gemm_bb(
    const u16* __restrict__ A, int lda, const u16* __restrict__ BT, int ldb,
    const float* __restrict__ bias, float* __restrict__ Cf, u16* __restrict__ Cb,
    int ldc, int K)
{
    gemm_body<ACT, OUTF, OUTB>(A, lda, BT, ldb, bias, nullptr, Cf, Cb, ldc, K,
                               blockIdx.y << 6, blockIdx.x << 6);
}

// fused dual-output GEMM (N=768, two bias vectors), bf16 out
template <int ACT>
__global__ __launch_bounds__(256) void k_gemm_bb2(
    const u16* __restrict__ A, int lda, const u16* __restrict__ BT, int ldb,
    const float* __restrict__ bias0, const float* __restrict__ bias1,
    u16* __restrict__ Cb, int ldc, int K)
{
    gemm_body<ACT, false, true>(A, lda, BT, ldb, bias0, bias1, nullptr, Cb, ldc, K,
                                blockIdx.y << 6, blockIdx.x << 6);
}

// Qp[b, hd*384+j] = sum_d Qh[b, hd*64+d] * Wak[j, hd*64+d]   (bf16 out)
__global__ __launch_bounds__(256) void k_qp_bb(
    const u16* __restrict__ Qhb, const u16* __restrict__ WakB, u16* __restrict__ Qpb)
{
    int hd = blockIdx.z;
    gemm_body<0, false, true>(Qhb + hd * 64, 384, WakB + hd * 64, 384, nullptr, nullptr,
                              nullptr, Qpb + hd * 384, 2304, 64,
                              blockIdx.y << 6, blockIdx.x << 6);
}

// attn[b, hd*64+n] = sum_j vms[b, hd*384+j] * Wav[j, hd*64+n] + bav[hd*64+n]
__global__ __launch_bounds__(256) void k_attnout_bb(
    const u16* __restrict__ vmsb, const u16* __restrict__ WavT,
    const float* __restrict__ bav, u16* __restrict__ attnb)
{
    int hd = blockIdx.x;
    gemm_body<0, false, true>(vmsb + hd * 384, 2304, WavT + (size_t)hd * 64 * 384, 384,
                              bav + hd * 64, nullptr, nullptr, attnb + hd * 64, 384, 384,
                              blockIdx.y << 6, 0);
}

// fused score-bias MLP: one block per b (192 threads); hid + Wss2 in LDS
__global__ __launch_bounds__(192) void k_mlpbias(
    const float* __restrict__ sdiff, const float* __restrict__ Wss1,
    const float* __restrict__ bss1, const float* __restrict__ Wss2,
    const float* __restrict__ bss2, float* __restrict__ bias_s)
{
    __shared__ float sdS[32 * 12];
    __shared__ float hidS[32 * 193];
    __shared__ float w2S[1152];
    const int b = blockIdx.x;
    const int t = threadIdx.x;
    for (int i = t; i < 384; i += 192) sdS[i] = sdiff[(size_t)b * 384 + i];
    for (int i = t; i < 1152; i += 192) w2S[i] = fs(Wss2[i]);
    __syncthreads();
    {
        float w[12];
#pragma unroll
        for (int j = 0; j < 12; j++) w[j] = fs(Wss1[j * 192 + t]);
        float b1 = fs(bss1[t]);
        for (int k = 0; k < 32; k++) {
            float acc = b1;
#pragma unroll
            for (int j = 0; j < 12; j++) acc += sdS[k * 12 + j] * w[j];
            hidS[k * 193 + t] = gelu_f(acc);
        }
    }
    __syncthreads();
    {
        int k = t / 6, s = t - k * 6;
        float acc = fs(bss2[s]);
        for (int n = 0; n < 192; n++) acc += hidS[k * 193 + n] * w2S[n * 6 + s];
        bias_s[(size_t)(b * 32 + k) * 6 + s] = acc;
    }
}

// qkb[b,h]: one wave per (b,h)
__global__ void k_qkb_w(const float* __restrict__ Qh, const float* __restrict__ bak,
                        float* __restrict__ qkb, int BCc)
{
    int wid = (blockIdx.x * 256 + threadIdx.x) >> 6;
    int lane = threadIdx.x & 63;
    if (wid >= BCc * 6) return;
    int b = wid / 6, h = wid - b * 6;
    float acc = Qh[(size_t)b * 384 + h * 64 + lane] * fs(bak[h * 64 + lane]);
#pragma unroll
    for (int m = 1; m <= 32; m <<= 1) acc += __shfl_xor(acc, m);
    if (lane == 0) qkb[b * 6 + h] = acc;
}

// attention core, MFMA stages A+B:
//   A: kv(32x384) = gelu(nbr(32x32 bf16) @ WnpT^T + bnp)  -> kvsb (stride 392 u16)
//   B: scores(32x6) = kv @ q^T via MFMA on waves 0-1 -> sS; softmax -> wsx
//   C: vms = w @ kv (VALU, conflict-free column reads)
__global__ __launch_bounds__(384) void k_attnblk(
    const float* __restrict__ nbr, const u16* __restrict__ WnpT,
    const float* __restrict__ bnp, const u16* __restrict__ Qpb,
    const float* __restrict__ qkb, const float* __restrict__ bias_s,
    const int* __restrict__ rvalid, const float* __restrict__ anyv,
    u16* __restrict__ vmsb)
{
    __shared__ u16 kvsb[32 * 392];    // 25088 B
    __shared__ u16 qSb[6 * 392];      // 4704 B
    __shared__ float wsx[192];        // 768 B
    __shared__ float uSf[512];        // 2048 B: aS (32x32 u16) then sS (32x8 f32)
    u16* aS = (u16*)uSf;
    float* sS = uSf;
    const int b = blockIdx.x;
    const int t = threadIdx.x;
    const int lane = t & 63, wave = t >> 6;
    const int frm = lane & 15, frq = lane >> 4;
    // load q (bf16) to LDS, row stride 392 u16 (196 u32)
    for (int i = t; i < 1152; i += 384) {
        int h = i / 192, k2 = i - h * 192;
        ((u32*)qSb)[h * 196 + k2] = ((const u32*)(Qpb + (size_t)b * 2304))[i];
    }
    // fill aS: nbr (32x30 f32) -> bf16 32x32, cols 30/31 zero
    {
        const float* nr = nbr + (size_t)b * 960;
        for (int i = t; i < 1024; i += 384) {
            int r = i >> 5, cc = i & 31;
            aS[r * 32 + cc] = (cc < 30) ? f2b(nr[r * 30 + cc]) : (u16)0;
        }
    }
    __syncthreads();
    {   // stage A (MFMA): wave covers cols wave*64..+63
        bf16x8 a0 = *(const bf16x8*)&aS[frm * 32 + (frq << 3)];
        bf16x8 a1 = *(const bf16x8*)&aS[(16 + frm) * 32 + (frq << 3)];
        const f32x4 z = {0.f, 0.f, 0.f, 0.f};
        f32x4 acc0[4] = {z, z, z, z};
        f32x4 acc1[4] = {z, z, z, z};
#pragma unroll
        for (int ct = 0; ct < 4; ct++) {
            int col = (wave << 6) + (ct << 4) + frm;
            bf16x8 bf = *(const bf16x8*)&WnpT[col * 32 + (frq << 3)];
            acc0[ct] = __builtin_amdgcn_mfma_f32_16x16x32_bf16(a0, bf, acc0[ct], 0, 0, 0);
            acc1[ct] = __builtin_amdgcn_mfma_f32_16x16x32_bf16(a1, bf, acc1[ct], 0, 0, 0);
        }
#pragma unroll
        for (int ct = 0; ct < 4; ct++) {
            int col = (wave << 6) + (ct << 4) + frm;
            float bb = fs(bnp[col]);
#pragma unroll
            for (int r = 0; r < 4; r++) {
                int row0 = (frq << 2) + r;
                kvsb[row0 * 392 + col] = f2b(gelu_f(acc0[ct][r] + bb));
                kvsb[(row0 + 16) * 392 + col] = f2b(gelu_f(acc1[ct][r] + bb));
            }
        }
    }
    __syncthreads();
    if (wave < 2) {   // stage B (MFMA): scores[k][h], wave = k row-tile
        f32x4 accs = {0.f, 0.f, 0.f, 0.f};
#pragma unroll
        for (int ks = 0; ks < 12; ks++) {
            bf16x8 af = *(const bf16x8*)&kvsb[((wave << 4) + frm) * 392 + (ks << 5) + (frq << 3)];
            int hh = (frm < 6) ? frm : 0;
            bf16x8 bf = *(const bf16x8*)&qSb[hh * 392 + (ks << 5) + (frq << 3)];
            accs = __builtin_amdgcn_mfma_f32_16x16x32_bf16(af, bf, accs, 0, 0, 0);
        }
        if (frm < 6) {
#pragma unroll
            for (int r = 0; r < 4; r++)
                sS[((wave << 4) + (frq << 2) + r) * 8 + frm] = accs[r];
        }
    }
    __syncthreads();
    if (t < 192) {   // softmax over k per head
        int h = t >> 5, k = t & 31;
        float s = (sS[k * 8 + h] + qkb[b * 6 + h]) * 0.125f
                + bias_s[(size_t)(b * 32 + k) * 6 + h];
        bool ve = (rvalid[b * 32 + k] != 0) || (anyv[b] == 0.f && k == 0);
        s = ve ? s : -10000.f;
        float mx = s;
        mx = fmaxf(mx, __shfl_xor(mx, 1));
        mx = fmaxf(mx, __shfl_xor(mx, 2));
        mx = fmaxf(mx, __shfl_xor(mx, 4));
        mx = fmaxf(mx, __shfl_xor(mx, 8));
        mx = fmaxf(mx, __shfl_xor(mx, 16));
        float e = expf(s - mx);
        float sum = e;
        sum += __shfl_xor(sum, 1);
        sum += __shfl_xor(sum, 2);
        sum += __shfl_xor(sum, 4);
        sum += __shfl_xor(sum, 8);
        sum += __shfl_xor(sum, 16);
        wsx[h * 32 + k] = e / sum;
    }
    __syncthreads();
    {   // stage C: vms[h][t] = sum_k w[h][k]*kv[k][t] -> bf16
        float a0 = 0.f, a1 = 0.f, a2 = 0.f, a3 = 0.f, a4 = 0.f, a5 = 0.f;
        for (int k = 0; k < 32; k++) {
            float kvv = b2f(kvsb[k * 392 + t]);
            a0 += wsx[k] * kvv;
            a1 += wsx[32 + k] * kvv;
            a2 += wsx[64 + k] * kvv;
            a3 += wsx[96 + k] * kvv;
            a4 += wsx[128 + k] * kvv;
            a5 += wsx[160 + k] * kvv;
        }
        u16* vp = vmsb + (size_t)b * 2304;
        vp[t] = f2b(a0);
        vp[384 + t] = f2b(a1);
        vp[768 + t] = f2b(a2);
        vp[1152 + t] = f2b(a3);
        vp[1536 + t] = f2b(a4);
        vp[1920 + t] = f2b(a5);
    }
}

__global__ void k_ctxout(const float* __restrict__ ctx, const float* __restrict__ anyv,
                         const float* __restrict__ fctx, float* __restrict__ out, int BCc)
{
    int id = blockIdx.x * 256 + threadIdx.x;
    if (id >= BCc * 384) return;
    int b = id / 384, c = id - b * 384;
    float v = (anyv[b] > 0.f) ? ctx[id] : fs(fctx[c]);
    out[id] = fin(v);
}

// assemble trust-input X as bf16, row stride 448; tq read from qtqb cols 384+
__global__ void k_xtc_b(const u16* __restrict__ qtqb, const int* __restrict__ qcode,
                        const float* __restrict__ Etr, const float* __restrict__ gst,
                        u16* __restrict__ Xb, int BCc)
{
    int id = blockIdx.x * 256 + threadIdx.x;
    if (id >= BCc * 448) return;
    int b = id / 448, c = id - b * 448;
    if (c < 384) { Xb[id] = qtqb[(size_t)b * 768 + 384 + c]; return; }
    float v;
    if (c < 416) v = fs(Etr[min(max(qcode[b], 0), 20) * 32 + (c - 384)]);
    else if (c < 420) v = gst[(size_t)b * 4 + (c - 416)];
    else v = 0.f;
    Xb[id] = f2b(v);
}

// swb[b,s]: one wave per (b,s); s1 read as bf16 from hs1b cols 384+
__global__ void k_swb_w(const u16* __restrict__ hs1b, const float* __restrict__ Wsw2,
                        const float* __restrict__ bsw2, float* __restrict__ swb, int BCc)
{
    int wid = (blockIdx.x * 256 + threadIdx.x) >> 6;
    int lane = threadIdx.x & 63;
    if (wid >= BCc * 6) return;
    int b = wid / 6, s = wid - b * 6;
    float acc = 0.f;
#pragma unroll
    for (int i = 0; i < 6; i++) {
        int n = lane + 64 * i;
        acc += b2f(hs1b[(size_t)b * 768 + 384 + n]) * fs(Wsw2[n * 6 + s]);
    }
#pragma unroll
    for (int m = 1; m <= 32; m <<= 1) acc += __shfl_xor(acc, m);
    if (lane == 0) swb[b * 6 + s] = acc + fs(bsw2[s]);
}

// transfer: one wave per (b, s-pair)
__global__ void k_transfer_w(const float* __restrict__ nbr, const int* __restrict__ rsmask,
                             const int* __restrict__ rvalid, const float* __restrict__ swb,
                             const float* __restrict__ anyv, const float* __restrict__ sscale,
                             const float* __restrict__ fshift, float* __restrict__ out, int BCc)
{
    int wid = (blockIdx.x * 256 + threadIdx.x) >> 6;
    int lane = threadIdx.x & 63;
    if (wid >= BCc * 3) return;
    int b = wid / 3, s2 = wid - b * 3;
    int s = s2 * 2 + (lane >> 5), k = lane & 31;
    if (anyv[b] <= 0.f) {
        if (k == 0) out[b * 6 + s] = fin(fs(fshift[s]));
        return;
    }
    int gk = b * 32 + k;
    const float* nr = nbr + (size_t)gk * 30;
    float wb = swb[b * 6 + s] * 0.1f;
    bool m = (rvalid[gk] != 0) && (rsmask[gk * 6 + s] != 0);
    float wv = m ? (nr[28] + nr[29] * 0.5f + wb) : -10000.f;
    float mx = wv;
#pragma unroll
    for (int mm = 1; mm <= 16; mm <<= 1) mx = fmaxf(mx, __shfl_xor(mx, mm));
    float e = expf(wv - mx);
    float num = e * nr[s], den = e;
#pragma unroll
    for (int mm = 1; mm <= 16; mm <<= 1) {
        num += __shfl_xor(num, mm);
        den += __shfl_xor(den, mm);
    }
    if (k == 0) out[b * 6 + s] = fin((num / den) * fs(sscale[s]));
}

// trust: one wave per (b,s); each lane covers 3 hidden units
__global__ void k_trust_w(const float* __restrict__ tcp, const float* __restrict__ pst,
                          const float* __restrict__ Wtp1, const float* __restrict__ Wtp2,
                          const float* __restrict__ btp2, float* __restrict__ out, int BCc)
{
    int wid = (blockIdx.x * 256 + threadIdx.x) >> 6;
    int lane = threadIdx.x & 63;
    if (wid >= BCc * 6) return;
    int b = wid / 6, s = wid - b * 6;
    const float* ps = pst + (size_t)b * 24 + s * 4;
    float p0 = ps[0], p1 = ps[1], p2 = ps[2], p3 = ps[3];
    float acc = 0.f;
#pragma unroll
    for (int i = 0; i < 3; i++) {
        int j = lane + 64 * i;
        float pre = tcp[(size_t)b * 192 + j];
        pre += p0 * fs(Wtp1[(size_t)384 * 192 + j]);
        pre += p1 * fs(Wtp1[(size_t)385 * 192 + j]);
        pre += p2 * fs(Wtp1[(size_t)386 * 192 + j]);
        pre += p3 * fs(Wtp1[(size_t)387 * 192 + j]);
        acc += gelu_f(pre) * fs(Wtp2[j]);
    }
#pragma unroll
    for (int m = 1; m <= 32; m <<= 1) acc += __shfl_xor(acc, m);
    if (lane == 0) {
        float tv = 1.f / (1.f + expf(-(acc + fs(btp2[0]))));
        out[b * 6 + s] = fin(tv);
    }
}

#define L1(total) <<<((total) + 255) / 256, 256, 0, stream>>>
#define LW(nwaves) <<<(((nwaves) * 64) + 255) / 256, 256, 0, stream>>>

extern "C" void kernel_launch(void* const* d_in, const int* in_sizes, int n_in,
                              void* d_out, int out_size, void* d_ws, size_t ws_size,
                              hipStream_t stream)
{
    float* out = (float*)d_out;

    static const int EXP[45] = {
        2097152, 4096, 24576, 24576, 786432, 786432, 131072, 131072, 131072, 126,
        196608, 384, 336, 11520, 384, 147456, 384, 147456, 384, 147456, 384,
        2304, 192, 1152, 6, 147456, 384, 147456, 384, 147456, 384, 2304, 6,
        672, 196608, 384, 161280, 384, 74496, 192, 192, 1, 6, 6, 384
    };
    if (n_in != 45) {
        fill_kernel L1(out_size)(out, out_size, 580.0f);
        return;
    }
    for (int i = 0; i < 45; i++) {
        if (in_sizes[i] != EXP[i]) {
            fill_kernel L1(out_size)(out, out_size, 600.0f + 4.0f * i);
            return;
        }
    }

    const float* i_qe    = (const float*)d_in[0];
    const int*   i_qcode = (const int*)d_in[1];
    const float* i_qobs  = (const float*)d_in[2];
    const float* i_qmask = (const float*)d_in[3];
    const float* i_rshift= (const float*)d_in[4];
    const int*   i_rsmask= (const int*)d_in[5];
    const int*   i_rcodes= (const int*)d_in[6];
    const float* i_rdist = (const float*)d_in[7];
    const int*   i_rvalid= (const int*)d_in[8];
    const float* i_rc    = (const float*)d_in[9];
    const float* i_Wqp   = (const float*)d_in[10];
    const float* i_bqp   = (const float*)d_in[11];
    const float* i_Eres  = (const float*)d_in[12];
    const float* i_Wnp   = (const float*)d_in[13];
    const float* i_bnp   = (const float*)d_in[14];
    const float* i_Waq   = (const float*)d_in[15];
    const float* i_baq   = (const float*)d_in[16];
    const float* i_Wak   = (const float*)d_in[17];
    const float* i_bak   = (const float*)d_in[18];
    const float* i_Wav   = (const float*)d_in[19];
    const float* i_bav   = (const float*)d_in[20];
    const float* i_Wss1  = (const float*)d_in[21];
    const float* i_bss1  = (const float*)d_in[22];
    const float* i_Wss2  = (const float*)d_in[23];
    const float* i_bss2  = (const float*)d_in[24];
    const float* i_Wcp1  = (const float*)d_in[25];
    const float* i_bcp1  = (const float*)d_in[26];
    const float* i_Wcp2  = (const float*)d_in[27];
    const float* i_bcp2  = (const float*)d_in[28];
    const float* i_Wsw1  = (const float*)d_in[29];
    const float* i_bsw1  = (const float*)d_in[30];
    const float* i_Wsw2  = (const float*)d_in[31];
    const float* i_bsw2  = (const float*)d_in[32];
    const float* i_Etr   = (const float*)d_in[33];
    const float* i_Wtq   = (const float*)d_in[34];
    const float* i_btq   = (const float*)d_in[35];
    const float* i_Wtc   = (const float*)d_in[36];
    const float* i_btc   = (const float*)d_in[37];
    const float* i_Wtp1  = (const float*)d_in[38];
    const float* i_btp1  = (const float*)d_in[39];
    const float* i_Wtp2  = (const float*)d_in[40];
    const float* i_btp2  = (const float*)d_in[41];
    const float* i_sscale= (const float*)d_in[42];
    const float* i_fshift= (const float*)d_in[43];
    const float* i_fctx  = (const float*)d_in[44];

    auto layoutBytes = [](int bc) -> size_t {
        auto al = [](size_t x) { return (x + 255) & ~(size_t)255; };
        size_t off = 0;
        off += al(2097152ull * 2);              // qeb
        off += al(393216ull * 2);               // WqtqT
        off += al(147456ull * 2) * 4;           // WaqT, WakB, WavT, Wcp2T
        off += al(294912ull * 2);               // Whs1T
        off += al(172032ull * 2);               // WtcT
        off += al(73728ull * 2);                // Wtp1T
        off += al(12288ull * 2);                // WnpT
        size_t nb = (size_t)bc * 32;
        off += al(nb * 30 * 4) + al(nb * 12 * 4) + al(nb * 6 * 4);
        off += al((size_t)bc * 384 * 4) * 2;    // Qhf, ctxf
        off += al((size_t)bc * 192 * 4);        // tcpf
        off += al((size_t)bc * 2304 * 2) * 2;   // Qpb, vmsb
        off += al((size_t)bc * 768 * 2) * 2;    // qtqb, hs1b
        off += al((size_t)bc * 384 * 2) * 3;    // Qhb, attnb, tcb
        off += al((size_t)bc * 448 * 2);        // Xfb
        off += al((size_t)bc * 6 * 4) * 2 + al((size_t)bc * 24 * 4)
             + al((size_t)bc * 4 * 4) + al((size_t)bc * 4);
        return off;
    };
    const int cand[7] = {4096, 2048, 1024, 512, 256, 128, 64};
    int BCc = 64;
    for (int i = 0; i < 7; i++) {
        if (layoutBytes(cand[i]) <= ws_size) { BCc = cand[i]; break; }
    }
    const int NBc = BCc * 32;

    char* wsb = (char*)d_ws;
    size_t off = 0;
    auto allocB = [&](size_t bytes) -> void* {
        void* p = (void*)(wsb + off);
        off = (off + bytes + 255) & ~(size_t)255;
        return p;
    };
    u16* qeb    = (u16*)allocB(2097152ull * 2);
    u16* WqtqT  = (u16*)allocB(393216ull * 2);
    u16* WaqT   = (u16*)allocB(147456ull * 2);
    u16* WakB   = (u16*)allocB(147456ull * 2);
    u16* WavT   = (u16*)allocB(147456ull * 2);
    u16* Wcp2T  = (u16*)allocB(147456ull * 2);
    u16* Whs1T  = (u16*)allocB(294912ull * 2);
    u16* WtcT   = (u16*)allocB(172032ull * 2);
    u16* Wtp1T  = (u16*)allocB(73728ull * 2);
    u16* WnpT   = (u16*)allocB(12288ull * 2);
    float* nbr   = (float*)allocB((size_t)NBc * 30 * 4);
    float* sdiff = (float*)allocB((size_t)NBc * 12 * 4);
    float* bias_s= (float*)allocB((size_t)NBc * 6 * 4);
    float* Qhf   = (float*)allocB((size_t)BCc * 384 * 4);
    float* ctxf  = (float*)allocB((size_t)BCc * 384 * 4);
    float* tcpf  = (float*)allocB((size_t)BCc * 192 * 4);
    u16*   Qpb   = (u16*)allocB((size_t)BCc * 2304 * 2);
    u16*   vmsb  = (u16*)allocB((size_t)BCc * 2304 * 2);
    u16*   qtqb  = (u16*)allocB((size_t)BCc * 768 * 2);
    u16*   hs1b  = (u16*)allocB((size_t)BCc * 768 * 2);
    u16*   Qhb   = (u16*)allocB((size_t)BCc * 384 * 2);
    u16*   attnb = (u16*)allocB((size_t)BCc * 384 * 2);
    u16*   tcb   = (u16*)allocB((size_t)BCc * 384 * 2);
    u16*   Xfb   = (u16*)allocB((size_t)BCc * 448 * 2);
    float* swbf  = (float*)allocB((size_t)BCc * 6 * 4);
    float* qkbf  = (float*)allocB((size_t)BCc * 6 * 4);
    float* pstf  = (float*)allocB((size_t)BCc * 24 * 4);
    float* gstf  = (float*)allocB((size_t)BCc * 4 * 4);
    float* anyf  = (float*)allocB((size_t)BCc * 4);

    if (off > ws_size) {
        fill_kernel L1(out_size)(out, out_size, 1000.0f);
        return;
    }

    k_cvt L1(2097152)(i_qe, qeb, 2097152);
    k_cvtT L1(196608)(i_Wqp, WqtqT, 512, 384, 512, 196608);
    k_cvtT L1(196608)(i_Wtq, WqtqT + 196608, 512, 384, 512, 196608);
    k_cvtT L1(147456)(i_Waq, WaqT, 384, 384, 384, 147456);
    k_cvt L1(147456)(i_Wak, WakB, 147456);
    k_cvtT L1(147456)(i_Wav, WavT, 384, 384, 384, 147456);
    k_cvtT L1(147456)(i_Wcp2, Wcp2T, 384, 384, 384, 147456);
    k_cvtT L1(147456)(i_Wcp1, Whs1T, 384, 384, 384, 147456);
    k_cvtT L1(147456)(i_Wsw1, Whs1T + 147456, 384, 384, 384, 147456);
    k_cvtT L1(172032)(i_Wtc, WtcT, 420, 384, 448, 172032);
    k_cvtT L1(73728)(i_Wtp1, Wtp1T, 384, 192, 384, 73728);
    k_cvtT L1(12288)(i_Wnp, WnpT, 30, 384, 32, 12288);

    for (int c = 0; c < 4096 / BCc; c++) {
        const size_t B0 = (size_t)c * BCc;
        const dim3 g6(6, BCc / 64), g3(3, BCc / 64), g12(12, BCc / 64);
        const dim3 gqp(6, BCc / 64, 6), gao(6, BCc / 64);
        k_prep L1(NBc)(i_qobs + B0 * 6, i_qmask + B0 * 6, i_rshift + B0 * 192,
                       i_rsmask + B0 * 192, i_qcode + B0, i_rcodes + B0 * 32,
                       i_rdist + B0 * 32, i_rc, i_Eres, nbr, sdiff, NBc);
        k_statsS_w LW(BCc * 3)(nbr, i_rvalid + B0 * 32, pstf, BCc);
        k_statsG_w LW(BCc)(nbr, i_rvalid + B0 * 32, gstf, anyf, BCc);
        k_mlpbias<<<BCc, 192, 0, stream>>>(sdiff, i_Wss1, i_bss1, i_Wss2, i_bss2, bias_s);
        k_gemm_bb2<1><<<g12, 256, 0, stream>>>(
            qeb + B0 * 512, 512, WqtqT, 512, i_bqp, i_btq, qtqb, 768, 512);
        k_gemm_bb<0, true, true><<<g6, 256, 0, stream>>>(
            qtqb, 768, WaqT, 384, i_baq, Qhf, Qhb, 384, 384);
        k_qp_bb<<<gqp, 256, 0, stream>>>(Qhb, WakB, Qpb);
        k_qkb_w LW(BCc * 6)(Qhf, i_bak, qkbf, BCc);
        k_attnblk<<<BCc, 384, 0, stream>>>(nbr, WnpT, i_bnp, Qpb, qkbf, bias_s,
                                           i_rvalid + B0 * 32, anyf, vmsb);
        k_attnout_bb<<<gao, 256, 0, stream>>>(vmsb, WavT, i_bav, attnb);
        k_gemm_bb2<1><<<g12, 256, 0, stream>>>(
            attnb, 384, Whs1T, 384, i_bcp1, i_bsw1, hs1b, 768, 384);
        k_gemm_bb<0, true, false><<<g6, 256, 0, stream>>>(
            hs1b, 768, Wcp2T, 384, i_bcp2, ctxf, nullptr, 384, 384);
        k_swb_w LW(BCc * 6)(hs1b, i_Wsw2, i_bsw2, swbf, BCc);
        k_ctxout L1(BCc * 384)(ctxf, anyf, i_fctx, out + B0 * 384, BCc);
        k_xtc_b L1(BCc * 448)(qtqb, i_qcode + B0, i_Etr, gstf, Xfb, BCc);
        k_gemm_bb<1, false, true><<<g6, 256, 0, stream>>>(
            Xfb, 448, WtcT, 448, i_btc, nullptr, tcb, 384, 448);
        k_gemm_bb<0, true, false><<<g3, 256, 0, stream>>>(
            tcb, 384, Wtp1T, 384, i_btp1, tcpf, nullptr, 192, 384);
        k_trust_w LW(BCc * 6)(tcpf, pstf, i_Wtp1, i_Wtp2, i_btp2,
                              out + (size_t)4096 * 390 + B0 * 6, BCc);
        k_transfer_w LW(BCc * 3)(nbr, i_rsmask + B0 * 192, i_rvalid + B0 * 32, swbf, anyf,
                                 i_sscale, i_fshift, out + (size_t)4096 * 384 + B0 * 6, BCc);
    }
}

// Round 8
// 393.546 us; speedup vs baseline: 4.4638x; 1.1231x over previous
//
#include <hip/hip_runtime.h>

typedef unsigned short u16;
typedef unsigned int u32;
typedef __attribute__((ext_vector_type(8))) short bf16x8;
typedef __attribute__((ext_vector_type(4))) float f32x4;

__device__ __forceinline__ float fs(float f) {
    return (f == f && fabsf(f) < 1e30f) ? f : 0.f;
}
__device__ __forceinline__ float fin(float v) {
    return (v == v && fabsf(v) < 1e30f) ? v : 555.0f;
}
__device__ __forceinline__ u16 f2b(float f) {
    union { float f; unsigned int i; } w; w.f = f;
    unsigned int r = w.i + 0x7FFFu + ((w.i >> 16) & 1u);
    return (u16)(r >> 16);
}
__device__ __forceinline__ float b2f(u16 b) {
    union { unsigned int i; float f; } w; w.i = ((unsigned int)b) << 16;
    return w.f;
}
__device__ __forceinline__ float gelu_f(float x) {
    return 0.5f * x * (1.0f + erff(x * 0.70710678118654752440f));
}

__global__ void fill_kernel(float* __restrict__ out, int n, float val) {
    int i = blockIdx.x * 256 + threadIdx.x;
    if (i < n) out[i] = val;
}

// ---- one-shot weight conversion: 13 jobs fused into one kernel ----
// ws weight arena element offsets (u16), all naturally 256B-aligned:
//  qeb 0 | WqtqT 2097152 | WaqT 2490368 | WakB 2637824 | WavT 2785280
//  Wcp2T 2932736 | Whs1T 3080192 (cp1 then sw1) | WtcT 3375104
//  Wtp1T 3547136 | WnpT 3620864 | Wss2T 3633152 | end 3634304
struct CvtSrcs { const float* p[13]; };

__global__ void k_cvt_all(CvtSrcs sp, u16* __restrict__ w) {
    int id = blockIdx.x * 256 + threadIdx.x;
    if (id >= 3634304) return;
    if (id < 2097152) { w[id] = f2b(fs(sp.p[0][id])); return; }
    if (id >= 2637824 && id < 2785280) { w[id] = f2b(fs(sp.p[4][id - 2637824])); return; }
    const float* src; int local, K, N, Kp;
    if (id < 2293760)      { src = sp.p[1];  local = id - 2097152; K = 512; N = 384; Kp = 512; }
    else if (id < 2490368) { src = sp.p[2];  local = id - 2293760; K = 512; N = 384; Kp = 512; }
    else if (id < 2637824) { src = sp.p[3];  local = id - 2490368; K = 384; N = 384; Kp = 384; }
    else if (id < 2932736) { src = sp.p[5];  local = id - 2785280; K = 384; N = 384; Kp = 384; }
    else if (id < 3080192) { src = sp.p[6];  local = id - 2932736; K = 384; N = 384; Kp = 384; }
    else if (id < 3227648) { src = sp.p[7];  local = id - 3080192; K = 384; N = 384; Kp = 384; }
    else if (id < 3375104) { src = sp.p[8];  local = id - 3227648; K = 384; N = 384; Kp = 384; }
    else if (id < 3547136) { src = sp.p[9];  local = id - 3375104; K = 420; N = 384; Kp = 448; }
    else if (id < 3620864) { src = sp.p[10]; local = id - 3547136; K = 384; N = 192; Kp = 384; }
    else if (id < 3633152) { src = sp.p[11]; local = id - 3620864; K = 30;  N = 384; Kp = 32;  }
    else                   { src = sp.p[12]; local = id - 3633152; K = 192; N = 6;   Kp = 192; }
    int n = local / Kp, k = local - n * Kp;
    w[id] = (k < K) ? f2b(fs(src[(size_t)k * N + n])) : (u16)0;
}

// nbr row (30) + sdiff row (12), one thread per (b,k)
__global__ void k_prep(const float* __restrict__ qobs, const float* __restrict__ qmask,
                       const float* __restrict__ rshift, const int* __restrict__ rsmask,
                       const int* __restrict__ qcode, const int* __restrict__ rcodes,
                       const float* __restrict__ rdist, const float* __restrict__ rc_table,
                       const float* __restrict__ E_res,
                       float* __restrict__ nbr, float* __restrict__ sdiff, int NBc)
{
    int gk = blockIdx.x * 256 + threadIdx.x;
    if (gk >= NBc) return;
    int b = gk >> 5;
    int qc = qcode[b], rc = rcodes[gk];
    int qi = min(max(qc, 0), 20), ri = min(max(rc, 0), 20);
    float dist = fs(rdist[gk]);
    float same = (rc == qc) ? 1.f : 0.f;
    float* nr = nbr + (size_t)gk * 30;
    float* sd = sdiff + (size_t)gk * 12;
    for (int s = 0; s < 6; s++) {
        float rs = fs(rshift[gk * 6 + s]);
        bool m = rsmask[gk * 6 + s] != 0;
        float rq = rc_table[qi * 6 + s];
        float rr = rc_table[ri * 6 + s];
        bool rcv = (rq == rq) && (rr == rr) && fabsf(rq) < 1e30f && fabsf(rr) < 1e30f;
        float sh = (m && rcv) ? (rq + rs - rr) : rs;
        nr[s] = sh;
        nr[6 + s] = m ? 1.f : 0.f;
        float qm = fs(qmask[b * 6 + s]);
        sd[s] = (fs(qobs[b * 6 + s]) - sh) * qm;
        sd[6 + s] = qm;
    }
    for (int j = 0; j < 16; j++) nr[12 + j] = fs(E_res[ri * 16 + j]);
    nr[28] = dist;
    nr[29] = same;
}

// merged stats: 4 waves per b (sub 0-2: per-s pair stats, sub 3: global stats)
__global__ void k_stats_w(const float* __restrict__ nbr, const int* __restrict__ rvalid,
                          float* __restrict__ pst, float* __restrict__ gst,
                          float* __restrict__ anyv, int BCc)
{
    int wid = (blockIdx.x * 256 + threadIdx.x) >> 6;
    int lane = threadIdx.x & 63;
    if (wid >= BCc * 4) return;
    int b = wid >> 2, sub = wid & 3;
    if (sub < 3) {
        int s = sub * 2 + (lane >> 5), k = lane & 31;
        const float* nr = nbr + (size_t)(b * 32 + k) * 30;
        float vf = (rvalid[b * 32 + k] != 0) ? 1.f : 0.f;
        float vm = vf * nr[6 + s];
        float shv = nr[s], dist = nr[28], same = nr[29];
        float cnt = vm, msum = shv * vm, mdist = dist * vm, mst = same * vm;
#pragma unroll
        for (int m = 1; m <= 16; m <<= 1) {
            cnt += __shfl_xor(cnt, m);
            msum += __shfl_xor(msum, m);
            mdist += __shfl_xor(mdist, m);
            mst += __shfl_xor(mst, m);
        }
        float inv = 1.f / (cnt + 1e-8f);
        float mean = msum * inv;
        float dv = shv - mean;
        float var = dv * dv * vm;
#pragma unroll
        for (int m = 1; m <= 16; m <<= 1) var += __shfl_xor(var, m);
        var *= inv;
        if (k == 0) {
            float* p = pst + (size_t)b * 24 + s * 4;
            p[0] = cnt * (1.f / 32.f);
            p[1] = fminf(fmaxf(log1pf(var), 0.f), 5.f) * 0.2f;
            p[2] = mdist * inv;
            p[3] = mst * inv;
        }
    } else {
        int k = lane & 31;
        float svf = 0.f, sdm = 0.f, mdm = -1e30f, ssm = 0.f;
        if (lane < 32) {
            const float* nr = nbr + (size_t)(b * 32 + k) * 30;
            float vf = (rvalid[b * 32 + k] != 0) ? 1.f : 0.f;
            float dm = vf * nr[28];
            svf = vf; sdm = dm; mdm = dm; ssm = vf * nr[29];
        }
#pragma unroll
        for (int m = 1; m <= 32; m <<= 1) {
            svf += __shfl_xor(svf, m);
            sdm += __shfl_xor(sdm, m);
            mdm = fmaxf(mdm, __shfl_xor(mdm, m));
            ssm += __shfl_xor(ssm, m);
        }
        if (lane == 0) {
            float* g = gst + (size_t)b * 4;
            g[0] = sdm / (svf + 1e-8f);
            g[1] = mdm;
            g[2] = svf * (1.f / 32.f);
            g[3] = ssm * (1.f / 32.f);
            anyv[b] = (svf > 0.f) ? 1.f : 0.f;
        }
    }
}

// bf16 MFMA GEMM body: C = act(A @ BT^T + bias). bias1 (optional) for col>=384.
template <int ACT, bool OUTF, bool OUTB>
__device__ __forceinline__ void gemm_body(
    const u16* __restrict__ A, int lda,
    const u16* __restrict__ BT, int ldb,
    const float* __restrict__ bias, const float* __restrict__ bias1,
    float* __restrict__ Cf, u16* __restrict__ Cb, int ldc,
    int K, int m0, int n0)
{
    __shared__ u16 As[64 * 72];
    __shared__ u16 Bs[64 * 72];
    const int t = threadIdx.x;
    const int lane = t & 63, wave = t >> 6;
    const int wm = (wave & 1) << 5, wn = (wave >> 1) << 5;
    const int frm = lane & 15, frq = lane >> 4;
    const int r0 = t >> 3, c0 = (t & 7) << 3;
    const f32x4 z = {0.f, 0.f, 0.f, 0.f};
    f32x4 acc[2][2] = {{z, z}, {z, z}};
    for (int k0 = 0; k0 < K; k0 += 64) {
        *(bf16x8*)&As[r0 * 72 + c0]        = *(const bf16x8*)&A[(size_t)(m0 + r0) * lda + k0 + c0];
        *(bf16x8*)&As[(r0 + 32) * 72 + c0] = *(const bf16x8*)&A[(size_t)(m0 + r0 + 32) * lda + k0 + c0];
        *(bf16x8*)&Bs[r0 * 72 + c0]        = *(const bf16x8*)&BT[(size_t)(n0 + r0) * ldb + k0 + c0];
        *(bf16x8*)&Bs[(r0 + 32) * 72 + c0] = *(const bf16x8*)&BT[(size_t)(n0 + r0 + 32) * ldb + k0 + c0];
        __syncthreads();
#pragma unroll
        for (int kk = 0; kk < 2; kk++) {
            const int fo = (kk << 5) + (frq << 3);
            bf16x8 a0 = *(const bf16x8*)&As[(wm + frm) * 72 + fo];
            bf16x8 a1 = *(const bf16x8*)&As[(wm + 16 + frm) * 72 + fo];
            bf16x8 b0 = *(const bf16x8*)&Bs[(wn + frm) * 72 + fo];
            bf16x8 b1 = *(const bf16x8*)&Bs[(wn + 16 + frm) * 72 + fo];
            acc[0][0] = __builtin_amdgcn_mfma_f32_16x16x32_bf16(a0, b0, acc[0][0], 0, 0, 0);
            acc[0][1] = __builtin_amdgcn_mfma_f32_16x16x32_bf16(a0, b1, acc[0][1], 0, 0, 0);
            acc[1][0] = __builtin_amdgcn_mfma_f32_16x16x32_bf16(a1, b0, acc[1][0], 0, 0, 0);
            acc[1][1] = __builtin_amdgcn_mfma_f32_16x16x32_bf16(a1, b1, acc[1][1], 0, 0, 0);
        }
        __syncthreads();
    }
#pragma unroll
    for (int mi = 0; mi < 2; mi++) {
#pragma unroll
        for (int ni = 0; ni < 2; ni++) {
            int col = n0 + wn + (ni << 4) + frm;
            float bv = 0.f;
            if (bias) {
                if (bias1 && col >= 384) bv = fs(bias1[col - 384]);
                else bv = fs(bias[col]);
            }
#pragma unroll
            for (int r = 0; r < 4; r++) {
                int row = m0 + wm + (mi << 4) + (frq << 2) + r;
                float v = acc[mi][ni][r] + bv;
                if (ACT == 1) v = gelu_f(v);
                if (OUTF) Cf[(size_t)row * ldc + col] = v;
                if (OUTB) Cb[(size_t)row * ldc + col] = f2b(v);
            }
        }
    }
}

template <int ACT, bool OUTF, bool OUTB>
__global__ __launch_bounds__(256) void k_gemm_bb(
    const u16* __restrict__ A, int lda, const u16* __restrict__ BT, int ldb,
    const float* __restrict__ bias, float* __restrict__ Cf, u16* __restrict__ Cb,
    int ldc, int K)
{
    gemm_body<ACT, OUTF, OUTB>(A, lda, BT, ldb, bias, nullptr, Cf, Cb, ldc, K,
                               blockIdx.y << 6, blockIdx.x << 6);
}

// fused dual-output GEMM (N=768, two bias vectors), bf16 out
template <int ACT>
__global__ __launch_bounds__(256) void k_gemm_bb2(
    const u16* __restrict__ A, int lda, const u16* __restrict__ BT, int ldb,
    const float* __restrict__ bias0, const float* __restrict__ bias1,
    u16* __restrict__ Cb, int ldc, int K)
{
    gemm_body<ACT, false, true>(A, lda, BT, ldb, bias0, bias1, nullptr, Cb, ldc, K,
                                blockIdx.y << 6, blockIdx.x << 6);
}

// ctx GEMM with fused output epilogue: out = fin(anyv ? acc+bias : fctx)
__global__ __launch_bounds__(256) void k_gemm_ctx(
    const u16* __restrict__ A, int lda, const u16* __restrict__ BT, int ldb,
    const float* __restrict__ bias, const float* __restrict__ anyv,
    const float* __restrict__ fctx, float* __restrict__ outp, int ldc, int K)
{
    __shared__ u16 As[64 * 72];
    __shared__ u16 Bs[64 * 72];
    const int t = threadIdx.x;
    const int lane = t & 63, wave = t >> 6;
    const int m0 = blockIdx.y << 6, n0 = blockIdx.x << 6;
    const int wm = (wave & 1) << 5, wn = (wave >> 1) << 5;
    const int frm = lane & 15, frq = lane >> 4;
    const int r0 = t >> 3, c0 = (t & 7) << 3;
    const f32x4 z = {0.f, 0.f, 0.f, 0.f};
    f32x4 acc[2][2] = {{z, z}, {z, z}};
    for (int k0 = 0; k0 < K; k0 += 64) {
        *(bf16x8*)&As[r0 * 72 + c0]        = *(const bf16x8*)&A[(size_t)(m0 + r0) * lda + k0 + c0];
        *(bf16x8*)&As[(r0 + 32) * 72 + c0] = *(const bf16x8*)&A[(size_t)(m0 + r0 + 32) * lda + k0 + c0];
        *(bf16x8*)&Bs[r0 * 72 + c0]        = *(const bf16x8*)&BT[(size_t)(n0 + r0) * ldb + k0 + c0];
        *(bf16x8*)&Bs[(r0 + 32) * 72 + c0] = *(const bf16x8*)&BT[(size_t)(n0 + r0 + 32) * ldb + k0 + c0];
        __syncthreads();
#pragma unroll
        for (int kk = 0; kk < 2; kk++) {
            const int fo = (kk << 5) + (frq << 3);
            bf16x8 a0 = *(const bf16x8*)&As[(wm + frm) * 72 + fo];
            bf16x8 a1 = *(const bf16x8*)&As[(wm + 16 + frm) * 72 + fo];
            bf16x8 b0 = *(const bf16x8*)&Bs[(wn + frm) * 72 + fo];
            bf16x8 b1 = *(const bf16x8*)&Bs[(wn + 16 + frm) * 72 + fo];
            acc[0][0] = __builtin_amdgcn_mfma_f32_16x16x32_bf16(a0, b0, acc[0][0], 0, 0, 0);
            acc[0][1] = __builtin_amdgcn_mfma_f32_16x16x32_bf16(a0, b1, acc[0][1], 0, 0, 0);
            acc[1][0] = __builtin_amdgcn_mfma_f32_16x16x32_bf16(a1, b0, acc[1][0], 0, 0, 0);
            acc[1][1] = __builtin_amdgcn_mfma_f32_16x16x32_bf16(a1, b1, acc[1][1], 0, 0, 0);
        }
        __syncthreads();
    }
#pragma unroll
    for (int mi = 0; mi < 2; mi++) {
#pragma unroll
        for (int ni = 0; ni < 2; ni++) {
            int col = n0 + wn + (ni << 4) + frm;
            float bv = fs(bias[col]);
            float fv = fs(fctx[col]);
#pragma unroll
            for (int r = 0; r < 4; r++) {
                int row = m0 + wm + (mi << 4) + (frq << 2) + r;
                float v = acc[mi][ni][r] + bv;
                v = (anyv[row] > 0.f) ? v : fv;
                outp[(size_t)row * ldc + col] = fin(v);
            }
        }
    }
}

// Qp per head: A (K=64) staged once, loop 6 n-tiles. grid (BCc/64, 6 heads)
__global__ __launch_bounds__(256) void k_qp_loop(
    const u16* __restrict__ Qhb, const u16* __restrict__ WakB, u16* __restrict__ Qpb)
{
    __shared__ u16 As[64 * 72];
    __shared__ u16 Bs[64 * 72];
    const int t = threadIdx.x;
    const int lane = t & 63, wave = t >> 6;
    const int m0 = blockIdx.x << 6, hd = blockIdx.y;
    const int wm = (wave & 1) << 5, wn = (wave >> 1) << 5;
    const int frm = lane & 15, frq = lane >> 4;
    const int r0 = t >> 3, c0 = (t & 7) << 3;
    const f32x4 z = {0.f, 0.f, 0.f, 0.f};
    *(bf16x8*)&As[r0 * 72 + c0]        = *(const bf16x8*)&Qhb[(size_t)(m0 + r0) * 384 + hd * 64 + c0];
    *(bf16x8*)&As[(r0 + 32) * 72 + c0] = *(const bf16x8*)&Qhb[(size_t)(m0 + r0 + 32) * 384 + hd * 64 + c0];
    for (int nt = 0; nt < 6; nt++) {
        *(bf16x8*)&Bs[r0 * 72 + c0]        = *(const bf16x8*)&WakB[(size_t)(nt * 64 + r0) * 384 + hd * 64 + c0];
        *(bf16x8*)&Bs[(r0 + 32) * 72 + c0] = *(const bf16x8*)&WakB[(size_t)(nt * 64 + r0 + 32) * 384 + hd * 64 + c0];
        __syncthreads();
        f32x4 acc[2][2] = {{z, z}, {z, z}};
#pragma unroll
        for (int kk = 0; kk < 2; kk++) {
            const int fo = (kk << 5) + (frq << 3);
            bf16x8 a0 = *(const bf16x8*)&As[(wm + frm) * 72 + fo];
            bf16x8 a1 = *(const bf16x8*)&As[(wm + 16 + frm) * 72 + fo];
            bf16x8 b0 = *(const bf16x8*)&Bs[(wn + frm) * 72 + fo];
            bf16x8 b1 = *(const bf16x8*)&Bs[(wn + 16 + frm) * 72 + fo];
            acc[0][0] = __builtin_amdgcn_mfma_f32_16x16x32_bf16(a0, b0, acc[0][0], 0, 0, 0);
            acc[0][1] = __builtin_amdgcn_mfma_f32_16x16x32_bf16(a0, b1, acc[0][1], 0, 0, 0);
            acc[1][0] = __builtin_amdgcn_mfma_f32_16x16x32_bf16(a1, b0, acc[1][0], 0, 0, 0);
            acc[1][1] = __builtin_amdgcn_mfma_f32_16x16x32_bf16(a1, b1, acc[1][1], 0, 0, 0);
        }
#pragma unroll
        for (int mi = 0; mi < 2; mi++) {
#pragma unroll
            for (int ni = 0; ni < 2; ni++) {
                int col = nt * 64 + wn + (ni << 4) + frm;
#pragma unroll
                for (int r = 0; r < 4; r++) {
                    int row = m0 + wm + (mi << 4) + (frq << 2) + r;
                    Qpb[(size_t)row * 2304 + hd * 384 + col] = f2b(acc[mi][ni][r]);
                }
            }
        }
        __syncthreads();
    }
}

// attn[b, hd*64+n] = sum_j vms[b, hd*384+j] * Wav[j, hd*64+n] + bav[hd*64+n]
__global__ __launch_bounds__(256) void k_attnout_bb(
    const u16* __restrict__ vmsb, const u16* __restrict__ WavT,
    const float* __restrict__ bav, u16* __restrict__ attnb)
{
    int hd = blockIdx.x;
    gemm_body<0, false, true>(vmsb + hd * 384, 2304, WavT + (size_t)hd * 64 * 384, 384,
                              bav + hd * 64, nullptr, nullptr, attnb + hd * 64, 384, 384,
                              blockIdx.y << 6, 0);
}

// fused score-bias MLP: stage1 VALU, stage2 MFMA (wave 0). 192 threads.
__global__ __launch_bounds__(192) void k_mlpbias(
    const float* __restrict__ sdiff, const float* __restrict__ Wss1,
    const float* __restrict__ bss1, const u16* __restrict__ Wss2T,
    const float* __restrict__ bss2, float* __restrict__ bias_s)
{
    __shared__ float sdS[32 * 12];
    __shared__ u16 hidSb[32 * 200];
    const int b = blockIdx.x;
    const int t = threadIdx.x;
    for (int i = t; i < 384; i += 192) sdS[i] = sdiff[(size_t)b * 384 + i];
    __syncthreads();
    {
        float w[12];
#pragma unroll
        for (int j = 0; j < 12; j++) w[j] = fs(Wss1[j * 192 + t]);
        float b1 = fs(bss1[t]);
        for (int k = 0; k < 32; k++) {
            float acc = b1;
#pragma unroll
            for (int j = 0; j < 12; j++) acc += sdS[k * 12 + j] * w[j];
            hidSb[k * 200 + t] = f2b(gelu_f(acc));
        }
    }
    __syncthreads();
    if (t < 64) {
        const int frm = t & 15, frq = t >> 4;
        const f32x4 z = {0.f, 0.f, 0.f, 0.f};
        f32x4 acc0 = z, acc1 = z;
        const u16* bt = Wss2T + (frm < 6 ? frm : 0) * 192;
#pragma unroll
        for (int ks = 0; ks < 6; ks++) {
            bf16x8 bf = *(const bf16x8*)&bt[ks * 32 + (frq << 3)];
            bf16x8 a0 = *(const bf16x8*)&hidSb[frm * 200 + ks * 32 + (frq << 3)];
            bf16x8 a1 = *(const bf16x8*)&hidSb[(16 + frm) * 200 + ks * 32 + (frq << 3)];
            acc0 = __builtin_amdgcn_mfma_f32_16x16x32_bf16(a0, bf, acc0, 0, 0, 0);
            acc1 = __builtin_amdgcn_mfma_f32_16x16x32_bf16(a1, bf, acc1, 0, 0, 0);
        }
        if (frm < 6) {
            float bb = fs(bss2[frm]);
#pragma unroll
            for (int r = 0; r < 4; r++) {
                int kk = (frq << 2) + r;
                bias_s[(size_t)(b * 32 + kk) * 6 + frm] = acc0[r] + bb;
                bias_s[(size_t)(b * 32 + kk + 16) * 6 + frm] = acc1[r] + bb;
            }
        }
    }
}

// qkb[b,h]: one wave per (b,h), Qh read as bf16
__global__ void k_qkb_w(const u16* __restrict__ Qhb, const float* __restrict__ bak,
                        float* __restrict__ qkb, int BCc)
{
    int wid = (blockIdx.x * 256 + threadIdx.x) >> 6;
    int lane = threadIdx.x & 63;
    if (wid >= BCc * 6) return;
    int b = wid / 6, h = wid - b * 6;
    float acc = b2f(Qhb[(size_t)b * 384 + h * 64 + lane]) * fs(bak[h * 64 + lane]);
#pragma unroll
    for (int m = 1; m <= 32; m <<= 1) acc += __shfl_xor(acc, m);
    if (lane == 0) qkb[b * 6 + h] = acc;
}

// attention core, MFMA stages A+B (unchanged from round 7)
__global__ __launch_bounds__(384) void k_attnblk(
    const float* __restrict__ nbr, const u16* __restrict__ WnpT,
    const float* __restrict__ bnp, const u16* __restrict__ Qpb,
    const float* __restrict__ qkb, const float* __restrict__ bias_s,
    const int* __restrict__ rvalid, const float* __restrict__ anyv,
    u16* __restrict__ vmsb)
{
    __shared__ u16 kvsb[32 * 392];
    __shared__ u16 qSb[6 * 392];
    __shared__ float wsx[192];
    __shared__ float uSf[512];
    u16* aS = (u16*)uSf;
    float* sS = uSf;
    const int b = blockIdx.x;
    const int t = threadIdx.x;
    const int lane = t & 63, wave = t >> 6;
    const int frm = lane & 15, frq = lane >> 4;
    for (int i = t; i < 1152; i += 384) {
        int h = i / 192, k2 = i - h * 192;
        ((u32*)qSb)[h * 196 + k2] = ((const u32*)(Qpb + (size_t)b * 2304))[i];
    }
    {
        const float* nr = nbr + (size_t)b * 960;
        for (int i = t; i < 1024; i += 384) {
            int r = i >> 5, cc = i & 31;
            aS[r * 32 + cc] = (cc < 30) ? f2b(nr[r * 30 + cc]) : (u16)0;
        }
    }
    __syncthreads();
    {   // stage A (MFMA)
        bf16x8 a0 = *(const bf16x8*)&aS[frm * 32 + (frq << 3)];
        bf16x8 a1 = *(const bf16x8*)&aS[(16 + frm) * 32 + (frq << 3)];
        const f32x4 z = {0.f, 0.f, 0.f, 0.f};
        f32x4 acc0[4] = {z, z, z, z};
        f32x4 acc1[4] = {z, z, z, z};
#pragma unroll
        for (int ct = 0; ct < 4; ct++) {
            int col = (wave << 6) + (ct << 4) + frm;
            bf16x8 bf = *(const bf16x8*)&WnpT[col * 32 + (frq << 3)];
            acc0[ct] = __builtin_amdgcn_mfma_f32_16x16x32_bf16(a0, bf, acc0[ct], 0, 0, 0);
            acc1[ct] = __builtin_amdgcn_mfma_f32_16x16x32_bf16(a1, bf, acc1[ct], 0, 0, 0);
        }
#pragma unroll
        for (int ct = 0; ct < 4; ct++) {
            int col = (wave << 6) + (ct << 4) + frm;
            float bb = fs(bnp[col]);
#pragma unroll
            for (int r = 0; r < 4; r++) {
                int row0 = (frq << 2) + r;
                kvsb[row0 * 392 + col] = f2b(gelu_f(acc0[ct][r] + bb));
                kvsb[(row0 + 16) * 392 + col] = f2b(gelu_f(acc1[ct][r] + bb));
            }
        }
    }
    __syncthreads();
    if (wave < 2) {   // stage B (MFMA): scores[k][h]
        f32x4 accs = {0.f, 0.f, 0.f, 0.f};
#pragma unroll
        for (int ks = 0; ks < 12; ks++) {
            bf16x8 af = *(const bf16x8*)&kvsb[((wave << 4) + frm) * 392 + (ks << 5) + (frq << 3)];
            int hh = (frm < 6) ? frm : 0;
            bf16x8 bf = *(const bf16x8*)&qSb[hh * 392 + (ks << 5) + (frq << 3)];
            accs = __builtin_amdgcn_mfma_f32_16x16x32_bf16(af, bf, accs, 0, 0, 0);
        }
        if (frm < 6) {
#pragma unroll
            for (int r = 0; r < 4; r++)
                sS[((wave << 4) + (frq << 2) + r) * 8 + frm] = accs[r];
        }
    }
    __syncthreads();
    if (t < 192) {   // softmax
        int h = t >> 5, k = t & 31;
        float s = (sS[k * 8 + h] + qkb[b * 6 + h]) * 0.125f
                + bias_s[(size_t)(b * 32 + k) * 6 + h];
        bool ve = (rvalid[b * 32 + k] != 0) || (anyv[b] == 0.f && k == 0);
        s = ve ? s : -10000.f;
        float mx = s;
        mx = fmaxf(mx, __shfl_xor(mx, 1));
        mx = fmaxf(mx, __shfl_xor(mx, 2));
        mx = fmaxf(mx, __shfl_xor(mx, 4));
        mx = fmaxf(mx, __shfl_xor(mx, 8));
        mx = fmaxf(mx, __shfl_xor(mx, 16));
        float e = expf(s - mx);
        float sum = e;
        sum += __shfl_xor(sum, 1);
        sum += __shfl_xor(sum, 2);
        sum += __shfl_xor(sum, 4);
        sum += __shfl_xor(sum, 8);
        sum += __shfl_xor(sum, 16);
        wsx[h * 32 + k] = e / sum;
    }
    __syncthreads();
    {   // stage C
        float a0 = 0.f, a1 = 0.f, a2 = 0.f, a3 = 0.f, a4 = 0.f, a5 = 0.f;
        for (int k = 0; k < 32; k++) {
            float kvv = b2f(kvsb[k * 392 + t]);
            a0 += wsx[k] * kvv;
            a1 += wsx[32 + k] * kvv;
            a2 += wsx[64 + k] * kvv;
            a3 += wsx[96 + k] * kvv;
            a4 += wsx[128 + k] * kvv;
            a5 += wsx[160 + k] * kvv;
        }
        u16* vp = vmsb + (size_t)b * 2304;
        vp[t] = f2b(a0);
        vp[384 + t] = f2b(a1);
        vp[768 + t] = f2b(a2);
        vp[1152 + t] = f2b(a3);
        vp[1536 + t] = f2b(a4);
        vp[1920 + t] = f2b(a5);
    }
}

// assemble trust-input X as bf16, row stride 448; tq from qtqb cols 384+
__global__ void k_xtc_b(const u16* __restrict__ qtqb, const int* __restrict__ qcode,
                        const float* __restrict__ Etr, const float* __restrict__ gst,
                        u16* __restrict__ Xb, int BCc)
{
    int id = blockIdx.x * 256 + threadIdx.x;
    if (id >= BCc * 448) return;
    int b = id / 448, c = id - b * 448;
    if (c < 384) { Xb[id] = qtqb[(size_t)b * 768 + 384 + c]; return; }
    float v;
    if (c < 416) v = fs(Etr[min(max(qcode[b], 0), 20) * 32 + (c - 384)]);
    else if (c < 420) v = gst[(size_t)b * 4 + (c - 416)];
    else v = 0.f;
    Xb[id] = f2b(v);
}

// swb[b,s]: one wave per (b,s); s1 from hs1b cols 384+
__global__ void k_swb_w(const u16* __restrict__ hs1b, const float* __restrict__ Wsw2,
                        const float* __restrict__ bsw2, float* __restrict__ swb, int BCc)
{
    int wid = (blockIdx.x * 256 + threadIdx.x) >> 6;
    int lane = threadIdx.x & 63;
    if (wid >= BCc * 6) return;
    int b = wid / 6, s = wid - b * 6;
    float acc = 0.f;
#pragma unroll
    for (int i = 0; i < 6; i++) {
        int n = lane + 64 * i;
        acc += b2f(hs1b[(size_t)b * 768 + 384 + n]) * fs(Wsw2[n * 6 + s]);
    }
#pragma unroll
    for (int m = 1; m <= 32; m <<= 1) acc += __shfl_xor(acc, m);
    if (lane == 0) swb[b * 6 + s] = acc + fs(bsw2[s]);
}

// merged tail: 9 waves per b (sub 0-5: trust s=sub; sub 6-8: transfer s-pair)
__global__ void k_tail_w(const float* __restrict__ tcp, const float* __restrict__ pst,
                         const float* __restrict__ Wtp1, const float* __restrict__ Wtp2,
                         const float* __restrict__ btp2, float* __restrict__ outT,
                         const float* __restrict__ nbr, const int* __restrict__ rsmask,
                         const int* __restrict__ rvalid, const float* __restrict__ swb,
                         const float* __restrict__ anyv, const float* __restrict__ sscale,
                         const float* __restrict__ fshift, float* __restrict__ outX, int BCc)
{
    int wid = (blockIdx.x * 256 + threadIdx.x) >> 6;
    int lane = threadIdx.x & 63;
    if (wid >= BCc * 9) return;
    int b = wid / 9, sub = wid - b * 9;
    if (sub < 6) {
        int s = sub;
        const float* ps = pst + (size_t)b * 24 + s * 4;
        float p0 = ps[0], p1 = ps[1], p2 = ps[2], p3 = ps[3];
        float acc = 0.f;
#pragma unroll
        for (int i = 0; i < 3; i++) {
            int j = lane + 64 * i;
            float pre = tcp[(size_t)b * 192 + j];
            pre += p0 * fs(Wtp1[(size_t)384 * 192 + j]);
            pre += p1 * fs(Wtp1[(size_t)385 * 192 + j]);
            pre += p2 * fs(Wtp1[(size_t)386 * 192 + j]);
            pre += p3 * fs(Wtp1[(size_t)387 * 192 + j]);
            acc += gelu_f(pre) * fs(Wtp2[j]);
        }
#pragma unroll
        for (int m = 1; m <= 32; m <<= 1) acc += __shfl_xor(acc, m);
        if (lane == 0) {
            float tv = 1.f / (1.f + expf(-(acc + fs(btp2[0]))));
            outT[b * 6 + s] = fin(tv);
        }
    } else {
        int s2 = sub - 6;
        int s = s2 * 2 + (lane >> 5), k = lane & 31;
        if (anyv[b] <= 0.f) {
            if (k == 0) outX[b * 6 + s] = fin(fs(fshift[s]));
            return;
        }
        int gk = b * 32 + k;
        const float* nr = nbr + (size_t)gk * 30;
        float wb = swb[b * 6 + s] * 0.1f;
        bool m = (rvalid[gk] != 0) && (rsmask[gk * 6 + s] != 0);
        float wv = m ? (nr[28] + nr[29] * 0.5f + wb) : -10000.f;
        float mx = wv;
#pragma unroll
        for (int mm = 1; mm <= 16; mm <<= 1) mx = fmaxf(mx, __shfl_xor(mx, mm));
        float e = expf(wv - mx);
        float num = e * nr[s], den = e;
#pragma unroll
        for (int mm = 1; mm <= 16; mm <<= 1) {
            num += __shfl_xor(num, mm);
            den += __shfl_xor(den, mm);
        }
        if (k == 0) outX[b * 6 + s] = fin((num / den) * fs(sscale[s]));
    }
}

#define L1(total) <<<((total) + 255) / 256, 256, 0, stream>>>
#define LW(nwaves) <<<(((nwaves) * 64) + 255) / 256, 256, 0, stream>>>

extern "C" void kernel_launch(void* const* d_in, const int* in_sizes, int n_in,
                              void* d_out, int out_size, void* d_ws, size_t ws_size,
                              hipStream_t stream)
{
    float* out = (float*)d_out;

    static const int EXP[45] = {
        2097152, 4096, 24576, 24576, 786432, 786432, 131072, 131072, 131072, 126,
        196608, 384, 336, 11520, 384, 147456, 384, 147456, 384, 147456, 384,
        2304, 192, 1152, 6, 147456, 384, 147456, 384, 147456, 384, 2304, 6,
        672, 196608, 384, 161280, 384, 74496, 192, 192, 1, 6, 6, 384
    };
    if (n_in != 45) {
        fill_kernel L1(out_size)(out, out_size, 580.0f);
        return;
    }
    for (int i = 0; i < 45; i++) {
        if (in_sizes[i] != EXP[i]) {
            fill_kernel L1(out_size)(out, out_size, 600.0f + 4.0f * i);
            return;
        }
    }

    const float* i_qe    = (const float*)d_in[0];
    const int*   i_qcode = (const int*)d_in[1];
    const float* i_qobs  = (const float*)d_in[2];
    const float* i_qmask = (const float*)d_in[3];
    const float* i_rshift= (const float*)d_in[4];
    const int*   i_rsmask= (const int*)d_in[5];
    const int*   i_rcodes= (const int*)d_in[6];
    const float* i_rdist = (const float*)d_in[7];
    const int*   i_rvalid= (const int*)d_in[8];
    const float* i_rc    = (const float*)d_in[9];
    const float* i_Wqp   = (const float*)d_in[10];
    const float* i_bqp   = (const float*)d_in[11];
    const float* i_Eres  = (const float*)d_in[12];
    const float* i_Wnp   = (const float*)d_in[13];
    const float* i_bnp   = (const float*)d_in[14];
    const float* i_Waq   = (const float*)d_in[15];
    const float* i_baq   = (const float*)d_in[16];
    const float* i_Wak   = (const float*)d_in[17];
    const float* i_bak   = (const float*)d_in[18];
    const float* i_Wav   = (const float*)d_in[19];
    const float* i_bav   = (const float*)d_in[20];
    const float* i_Wss1  = (const float*)d_in[21];
    const float* i_bss1  = (const float*)d_in[22];
    const float* i_Wss2  = (const float*)d_in[23];
    const float* i_bss2  = (const float*)d_in[24];
    const float* i_Wcp1  = (const float*)d_in[25];
    const float* i_bcp1  = (const float*)d_in[26];
    const float* i_Wcp2  = (const float*)d_in[27];
    const float* i_bcp2  = (const float*)d_in[28];
    const float* i_Wsw1  = (const float*)d_in[29];
    const float* i_bsw1  = (const float*)d_in[30];
    const float* i_Wsw2  = (const float*)d_in[31];
    const float* i_bsw2  = (const float*)d_in[32];
    const float* i_Etr   = (const float*)d_in[33];
    const float* i_Wtq   = (const float*)d_in[34];
    const float* i_btq   = (const float*)d_in[35];
    const float* i_Wtc   = (const float*)d_in[36];
    const float* i_btc   = (const float*)d_in[37];
    const float* i_Wtp1  = (const float*)d_in[38];
    const float* i_btp1  = (const float*)d_in[39];
    const float* i_Wtp2  = (const float*)d_in[40];
    const float* i_btp2  = (const float*)d_in[41];
    const float* i_sscale= (const float*)d_in[42];
    const float* i_fshift= (const float*)d_in[43];
    const float* i_fctx  = (const float*)d_in[44];

    auto layoutBytes = [](int bc) -> size_t {
        auto al = [](size_t x) { return (x + 255) & ~(size_t)255; };
        size_t off = 0;
        off += al(3634304ull * 2);              // weight arena (incl. qeb)
        size_t nb = (size_t)bc * 32;
        off += al(nb * 30 * 4) + al(nb * 12 * 4) + al(nb * 6 * 4);
        off += al((size_t)bc * 192 * 4);        // tcpf
        off += al((size_t)bc * 2304 * 2) * 2;   // Qpb, vmsb
        off += al((size_t)bc * 768 * 2) * 2;    // qtqb, hs1b
        off += al((size_t)bc * 384 * 2) * 3;    // Qhb, attnb, tcb
        off += al((size_t)bc * 448 * 2);        // Xfb
        off += al((size_t)bc * 6 * 4) * 2 + al((size_t)bc * 24 * 4)
             + al((size_t)bc * 4 * 4) + al((size_t)bc * 4);
        return off;
    };
    const int cand[7] = {4096, 2048, 1024, 512, 256, 128, 64};
    int BCc = 64;
    for (int i = 0; i < 7; i++) {
        if (layoutBytes(cand[i]) <= ws_size) { BCc = cand[i]; break; }
    }
    const int NBc = BCc * 32;

    char* wsb = (char*)d_ws;
    size_t off = 0;
    auto allocB = [&](size_t bytes) -> void* {
        void* p = (void*)(wsb + off);
        off = (off + bytes + 255) & ~(size_t)255;
        return p;
    };
    u16* wsW = (u16*)allocB(3634304ull * 2);
    u16* qeb   = wsW;
    u16* WqtqT = wsW + 2097152;
    u16* WaqT  = wsW + 2490368;
    u16* WakB  = wsW + 2637824;
    u16* WavT  = wsW + 2785280;
    u16* Wcp2T = wsW + 2932736;
    u16* Whs1T = wsW + 3080192;
    u16* WtcT  = wsW + 3375104;
    u16* Wtp1T = wsW + 3547136;
    u16* WnpT  = wsW + 3620864;
    u16* Wss2T = wsW + 3633152;
    float* nbr   = (float*)allocB((size_t)NBc * 30 * 4);
    float* sdiff = (float*)allocB((size_t)NBc * 12 * 4);
    float* bias_s= (float*)allocB((size_t)NBc * 6 * 4);
    float* tcpf  = (float*)allocB((size_t)BCc * 192 * 4);
    u16*   Qpb   = (u16*)allocB((size_t)BCc * 2304 * 2);
    u16*   vmsb  = (u16*)allocB((size_t)BCc * 2304 * 2);
    u16*   qtqb  = (u16*)allocB((size_t)BCc * 768 * 2);
    u16*   hs1b  = (u16*)allocB((size_t)BCc * 768 * 2);
    u16*   Qhb   = (u16*)allocB((size_t)BCc * 384 * 2);
    u16*   attnb = (u16*)allocB((size_t)BCc * 384 * 2);
    u16*   tcb   = (u16*)allocB((size_t)BCc * 384 * 2);
    u16*   Xfb   = (u16*)allocB((size_t)BCc * 448 * 2);
    float* swbf  = (float*)allocB((size_t)BCc * 6 * 4);
    float* qkbf  = (float*)allocB((size_t)BCc * 6 * 4);
    float* pstf  = (float*)allocB((size_t)BCc * 24 * 4);
    float* gstf  = (float*)allocB((size_t)BCc * 4 * 4);
    float* anyf  = (float*)allocB((size_t)BCc * 4);

    if (off > ws_size) {
        fill_kernel L1(out_size)(out, out_size, 1000.0f);
        return;
    }

    CvtSrcs sp;
    sp.p[0] = i_qe;  sp.p[1] = i_Wqp;  sp.p[2] = i_Wtq;  sp.p[3] = i_Waq;
    sp.p[4] = i_Wak; sp.p[5] = i_Wav;  sp.p[6] = i_Wcp2; sp.p[7] = i_Wcp1;
    sp.p[8] = i_Wsw1; sp.p[9] = i_Wtc; sp.p[10] = i_Wtp1; sp.p[11] = i_Wnp;
    sp.p[12] = i_Wss2;
    k_cvt_all L1(3634304)(sp, wsW);

    for (int c = 0; c < 4096 / BCc; c++) {
        const size_t B0 = (size_t)c * BCc;
        const dim3 g6(6, BCc / 64), g3(3, BCc / 64), g12(12, BCc / 64);
        const dim3 gqp(BCc / 64, 6), gao(6, BCc / 64);
        k_prep L1(NBc)(i_qobs + B0 * 6, i_qmask + B0 * 6, i_rshift + B0 * 192,
                       i_rsmask + B0 * 192, i_qcode + B0, i_rcodes + B0 * 32,
                       i_rdist + B0 * 32, i_rc, i_Eres, nbr, sdiff, NBc);
        k_stats_w LW(BCc * 4)(nbr, i_rvalid + B0 * 32, pstf, gstf, anyf, BCc);
        k_mlpbias<<<BCc, 192, 0, stream>>>(sdiff, i_Wss1, i_bss1, Wss2T, i_bss2, bias_s);
        k_gemm_bb2<1><<<g12, 256, 0, stream>>>(
            qeb + B0 * 512, 512, WqtqT, 512, i_bqp, i_btq, qtqb, 768, 512);
        k_gemm_bb<0, false, true><<<g6, 256, 0, stream>>>(
            qtqb, 768, WaqT, 384, i_baq, nullptr, Qhb, 384, 384);
        k_qp_loop<<<gqp, 256, 0, stream>>>(Qhb, WakB, Qpb);
        k_qkb_w LW(BCc * 6)(Qhb, i_bak, qkbf, BCc);
        k_attnblk<<<BCc, 384, 0, stream>>>(nbr, WnpT, i_bnp, Qpb, qkbf, bias_s,
                                           i_rvalid + B0 * 32, anyf, vmsb);
        k_attnout_bb<<<gao, 256, 0, stream>>>(vmsb, WavT, i_bav, attnb);
        k_gemm_bb2<1><<<g12, 256, 0, stream>>>(
            attnb, 384, Whs1T, 384, i_bcp1, i_bsw1, hs1b, 768, 384);
        k_gemm_ctx<<<g6, 256, 0, stream>>>(
            hs1b, 768, Wcp2T, 384, i_bcp2, anyf, i_fctx, out + B0 * 384, 384, 384);
        k_swb_w LW(BCc * 6)(hs1b, i_Wsw2, i_bsw2, swbf, BCc);
        k_xtc_b L1(BCc * 448)(qtqb, i_qcode + B0, i_Etr, gstf, Xfb, BCc);
        k_gemm_bb<1, false, true><<<g6, 256, 0, stream>>>(
            Xfb, 448, WtcT, 448, i_btc, nullptr, tcb, 384, 448);
        k_gemm_bb<0, true, false><<<g3, 256, 0, stream>>>(
            tcb, 384, Wtp1T, 384, i_btp1, tcpf, nullptr, 192, 384);
        k_tail_w LW(BCc * 9)(tcpf, pstf, i_Wtp1, i_Wtp2, i_btp2,
                             out + (size_t)4096 * 390 + B0 * 6,
                             nbr, i_rsmask + B0 * 192, i_rvalid + B0 * 32, swbf, anyf,
                             i_sscale, i_fshift, out + (size_t)4096 * 384 + B0 * 6, BCc);
    }
}